// Round 1
// baseline (3526.617 us; speedup 1.0000x reference)
//
#include <hip/hip_runtime.h>

// Problem constants (match reference setup_inputs)
#define NN 30000      // nodes
#define NE 600000     // edges
#define DD 128        // feature dim
#define RR 7          // relations
#define GG 16         // graphs
#define LL 3          // layers

// ---------------------------------------------------------------------------
// GEMM: O = h (N x 128) @ B (128 x 1024), where
//   B[:, 0:128)   = Wl            -> hacc (with bias br+bl added)
//   B[:, 128+q*64)= Wr blocks     -> Z  (N x 896), Z[n][r*128+c] = (h @ Wr_block_r)[n][c]
// Tile: 64 rows x 64 cols per block, full K=128 in LDS. 256 threads, 4x4 micro-tile.
// ---------------------------------------------------------------------------
__global__ __launch_bounds__(256) void gemm_expand(
    const float* __restrict__ h,    // N x 128
    const float* __restrict__ Wl,   // 128 x 128
    const float* __restrict__ Wr,   // 896 x 128
    const float* __restrict__ br,   // 128
    const float* __restrict__ bl,   // 128
    float* __restrict__ hacc,       // N x 128
    float* __restrict__ Z,          // N x 896
    int N)
{
    __shared__ float As[64][132];   // 64 rows x 128 k, pad to 132 floats
    __shared__ float Bs[128][68];   // 128 k x 64 cols, pad to 68 floats

    const int tid = threadIdx.x;
    const int row0 = blockIdx.x * 64;
    const int coltile = blockIdx.y;        // 0..15

    // Load A tile: 64x128 = 2048 float4, 8 per thread
#pragma unroll
    for (int l = 0; l < 8; ++l) {
        int f = tid + l * 256;             // 0..2047
        int r = f >> 5;                    // 32 float4 per row
        int c4 = f & 31;
        int row = row0 + r;
        float4 v = make_float4(0.f, 0.f, 0.f, 0.f);
        if (row < N) v = *(const float4*)(h + (size_t)row * DD + c4 * 4);
        *(float4*)(&As[r][c4 * 4]) = v;
    }

    // B source pointer for this 64-col tile
    const float* bsrc;
    if (coltile < 2) {
        bsrc = Wl + coltile * 64;
    } else {
        int q = coltile - 2;               // 0..13
        bsrc = Wr + (size_t)(q >> 1) * DD * DD + (q & 1) * 64;
    }
    // Load B tile: 128x64 = 2048 float4, 8 per thread
#pragma unroll
    for (int l = 0; l < 8; ++l) {
        int f = tid + l * 256;
        int k = f >> 4;                    // 16 float4 per row
        int c4 = f & 15;
        float4 v = *(const float4*)(bsrc + (size_t)k * DD + c4 * 4);
        *(float4*)(&Bs[k][c4 * 4]) = v;
    }
    __syncthreads();

    const int cg = tid & 15;               // 16 col-groups of 4 cols
    const int rg = tid >> 4;               // 16 row-groups of 4 rows

    float4 acc[4];
#pragma unroll
    for (int i = 0; i < 4; ++i) acc[i] = make_float4(0.f, 0.f, 0.f, 0.f);

#pragma unroll 4
    for (int k = 0; k < 128; ++k) {
        float4 b = *(const float4*)(&Bs[k][cg * 4]);
        float a0 = As[rg * 4 + 0][k];
        float a1 = As[rg * 4 + 1][k];
        float a2 = As[rg * 4 + 2][k];
        float a3 = As[rg * 4 + 3][k];
        acc[0].x = fmaf(a0, b.x, acc[0].x); acc[0].y = fmaf(a0, b.y, acc[0].y);
        acc[0].z = fmaf(a0, b.z, acc[0].z); acc[0].w = fmaf(a0, b.w, acc[0].w);
        acc[1].x = fmaf(a1, b.x, acc[1].x); acc[1].y = fmaf(a1, b.y, acc[1].y);
        acc[1].z = fmaf(a1, b.z, acc[1].z); acc[1].w = fmaf(a1, b.w, acc[1].w);
        acc[2].x = fmaf(a2, b.x, acc[2].x); acc[2].y = fmaf(a2, b.y, acc[2].y);
        acc[2].z = fmaf(a2, b.z, acc[2].z); acc[2].w = fmaf(a2, b.w, acc[2].w);
        acc[3].x = fmaf(a3, b.x, acc[3].x); acc[3].y = fmaf(a3, b.y, acc[3].y);
        acc[3].z = fmaf(a3, b.z, acc[3].z); acc[3].w = fmaf(a3, b.w, acc[3].w);
    }

    const int gcol0 = coltile * 64 + cg * 4;   // global col 0..1023
    if (coltile < 2) {
        float4 vb = *(const float4*)(br + gcol0);
        float4 vb2 = *(const float4*)(bl + gcol0);
#pragma unroll
        for (int i = 0; i < 4; ++i) {
            int row = row0 + rg * 4 + i;
            if (row < N) {
                float4 v = acc[i];
                v.x += vb.x + vb2.x; v.y += vb.y + vb2.y;
                v.z += vb.z + vb2.z; v.w += vb.w + vb2.w;
                *(float4*)(hacc + (size_t)row * DD + gcol0) = v;
            }
        }
    } else {
        const int zc = gcol0 - 128;            // 0..895
#pragma unroll
        for (int i = 0; i < 4; ++i) {
            int row = row0 + rg * 4 + i;
            if (row < N) {
                *(float4*)(Z + (size_t)row * (RR * DD) + zc) = acc[i];
            }
        }
    }
}

// ---------------------------------------------------------------------------
// Edge scatter: hacc[out_e] += ew_e * Z[in_e][rel_e*128 : rel_e*128+128]
// 32 lanes per edge, float4 per lane, 4 fp32 atomics per lane.
// ---------------------------------------------------------------------------
__global__ __launch_bounds__(256) void scatter_add(
    const float* __restrict__ Z,
    const int* __restrict__ node_in,
    const int* __restrict__ node_out,
    const int* __restrict__ relation,
    const float* __restrict__ ew,
    float* __restrict__ hacc,
    int E)
{
    int t = blockIdx.x * 256 + threadIdx.x;
    int e = t >> 5;
    int lane = t & 31;
    if (e >= E) return;
    int ni = node_in[e];
    int no = node_out[e];
    int r = relation[e];
    float w = ew[e];
    float4 v = *(const float4*)(Z + (size_t)ni * (RR * DD) + r * DD + lane * 4);
    float* dst = hacc + (size_t)no * DD + lane * 4;
    atomicAdd(dst + 0, v.x * w);
    atomicAdd(dst + 1, v.y * w);
    atomicAdd(dst + 2, v.z * w);
    atomicAdd(dst + 3, v.w * w);
}

// ---------------------------------------------------------------------------
// ReLU copy (float4 granularity)
// ---------------------------------------------------------------------------
__global__ __launch_bounds__(256) void relu_copy(
    const float* __restrict__ in, float* __restrict__ out, int n4)
{
    int i = blockIdx.x * 256 + threadIdx.x;
    if (i < n4) {
        float4 v = ((const float4*)in)[i];
        v.x = fmaxf(v.x, 0.f); v.y = fmaxf(v.y, 0.f);
        v.z = fmaxf(v.z, 0.f); v.w = fmaxf(v.w, 0.f);
        ((float4*)out)[i] = v;
    }
}

// ---------------------------------------------------------------------------
// Graph segment sum: gf[n2g[n]] += nf[n]. node2graph is sorted; each 32-lane
// group handles 16 consecutive nodes, accumulating locally per graph run.
// ---------------------------------------------------------------------------
__global__ __launch_bounds__(256) void graph_sum(
    const float* __restrict__ nf,
    const int* __restrict__ n2g,
    float* __restrict__ gf,
    int N)
{
    int t = blockIdx.x * 256 + threadIdx.x;
    int chunk = t >> 5;
    int lane = t & 31;
    int n0 = chunk * 16;
    if (n0 >= N) return;
    int nend = n0 + 16; if (nend > N) nend = N;

    float4 acc = make_float4(0.f, 0.f, 0.f, 0.f);
    int curg = n2g[n0];
    for (int n = n0; n < nend; ++n) {
        int g = n2g[n];
        if (g != curg) {
            float* dst = gf + (size_t)curg * DD + lane * 4;
            atomicAdd(dst + 0, acc.x); atomicAdd(dst + 1, acc.y);
            atomicAdd(dst + 2, acc.z); atomicAdd(dst + 3, acc.w);
            acc = make_float4(0.f, 0.f, 0.f, 0.f);
            curg = g;
        }
        float4 v = *(const float4*)(nf + (size_t)n * DD + lane * 4);
        acc.x += v.x; acc.y += v.y; acc.z += v.z; acc.w += v.w;
    }
    float* dst = gf + (size_t)curg * DD + lane * 4;
    atomicAdd(dst + 0, acc.x); atomicAdd(dst + 1, acc.y);
    atomicAdd(dst + 2, acc.z); atomicAdd(dst + 3, acc.w);
}

// ---------------------------------------------------------------------------
extern "C" void kernel_launch(void* const* d_in, const int* in_sizes, int n_in,
                              void* d_out, int out_size, void* d_ws, size_t ws_size,
                              hipStream_t stream)
{
    const float* x        = (const float*)d_in[0];   // N x 128
    const int*   node_in  = (const int*)d_in[1];     // E
    const int*   node_out = (const int*)d_in[2];     // E
    const int*   relation = (const int*)d_in[3];     // E
    const float* ew       = (const float*)d_in[4];   // E
    const int*   n2g      = (const int*)d_in[5];     // N (sorted)
    const float* Wr       = (const float*)d_in[6];   // L x 896 x 128
    const float* br       = (const float*)d_in[7];   // L x 128
    const float* Wl       = (const float*)d_in[8];   // L x 128 x 128
    const float* bl       = (const float*)d_in[9];   // L x 128

    float* out = (float*)d_out;
    float* gf = out;                 // 16 x 128
    float* nf = out + GG * DD;       // 30000 x 128 (node_feature)

    // Workspace layout (138.24 MB total)
    float* Z    = (float*)d_ws;                    // N x 896
    float* hacc = Z + (size_t)NN * RR * DD;        // N x 128
    float* hbuf = hacc + (size_t)NN * DD;          // N x 128

    const int N = NN, E = NE;
    dim3 ggrid((N + 63) / 64, 16);

    const float* hin = x;
    for (int l = 0; l < LL; ++l) {
        const float* Wr_l = Wr + (size_t)l * RR * DD * DD;
        const float* Wl_l = Wl + (size_t)l * DD * DD;
        const float* br_l = br + (size_t)l * DD;
        const float* bl_l = bl + (size_t)l * DD;

        gemm_expand<<<ggrid, 256, 0, stream>>>(hin, Wl_l, Wr_l, br_l, bl_l, hacc, Z, N);
        scatter_add<<<(E * 32) / 256, 256, 0, stream>>>(Z, node_in, node_out, relation, ew, hacc, E);

        float* hout = (l == LL - 1) ? nf : hbuf;
        relu_copy<<<(N * DD / 4 + 255) / 256, 256, 0, stream>>>(hacc, hout, N * DD / 4);
        hin = hout;
    }

    // graph_feature = segment_sum(node_feature, node2graph)
    hipMemsetAsync(gf, 0, (size_t)GG * DD * sizeof(float), stream);
    int chunks = (N + 15) / 16;
    graph_sum<<<(chunks * 32 + 255) / 256, 256, 0, stream>>>(nf, n2g, gf, N);
}

// Round 2
// 790.388 us; speedup vs baseline: 4.4619x; 4.4619x over previous
//
#include <hip/hip_runtime.h>

// Problem constants (match reference setup_inputs)
#define NN 30000      // nodes
#define NE 600000     // edges
#define DD 128        // feature dim
#define RR 7          // relations
#define GG 16         // graphs
#define LL 3          // layers

// ---- bf16 helpers (manual, avoid header API uncertainty) -------------------
__device__ __forceinline__ unsigned short f2bf(float f) {
    unsigned u = __float_as_uint(f);
    unsigned r = (u + 0x7fffu + ((u >> 16) & 1u)) >> 16;   // round-nearest-even
    return (unsigned short)r;
}

// ---------------------------------------------------------------------------
// GEMM: O = h (N x 128) @ B (128 x 1024), where
//   B[:, 0:128)   = Wl  -> hacc (fp32, with bias br+bl added)
//   B[:, 128+...) = Wr  -> Zb (bf16, N x 896), Zb[n][r*128+c] = (h @ Wr_r)[n][c]
// Tile: 64 rows x 64 cols per block, full K=128 in LDS. 256 threads, 4x4 micro.
// ---------------------------------------------------------------------------
__global__ __launch_bounds__(256) void gemm_expand(
    const float* __restrict__ h,    // N x 128
    const float* __restrict__ Wl,   // 128 x 128
    const float* __restrict__ Wr,   // 896 x 128  (7 blocks of 128x128)
    const float* __restrict__ br,   // 128
    const float* __restrict__ bl,   // 128
    float* __restrict__ hacc,       // N x 128
    unsigned short* __restrict__ Zb,// N x 896 (bf16)
    int N)
{
    __shared__ float As[64][132];
    __shared__ float Bs[128][68];

    const int tid = threadIdx.x;
    const int row0 = blockIdx.x * 64;
    const int coltile = blockIdx.y;        // 0..15

#pragma unroll
    for (int l = 0; l < 8; ++l) {
        int f = tid + l * 256;             // 0..2047
        int r = f >> 5;
        int c4 = f & 31;
        int row = row0 + r;
        float4 v = make_float4(0.f, 0.f, 0.f, 0.f);
        if (row < N) v = *(const float4*)(h + (size_t)row * DD + c4 * 4);
        *(float4*)(&As[r][c4 * 4]) = v;
    }

    const float* bsrc;
    if (coltile < 2) {
        bsrc = Wl + coltile * 64;
    } else {
        int q = coltile - 2;               // 0..13
        bsrc = Wr + (size_t)(q >> 1) * DD * DD + (q & 1) * 64;
    }
#pragma unroll
    for (int l = 0; l < 8; ++l) {
        int f = tid + l * 256;
        int k = f >> 4;
        int c4 = f & 15;
        float4 v = *(const float4*)(bsrc + (size_t)k * DD + c4 * 4);
        *(float4*)(&Bs[k][c4 * 4]) = v;
    }
    __syncthreads();

    const int cg = tid & 15;
    const int rg = tid >> 4;

    float4 acc[4];
#pragma unroll
    for (int i = 0; i < 4; ++i) acc[i] = make_float4(0.f, 0.f, 0.f, 0.f);

#pragma unroll 4
    for (int k = 0; k < 128; ++k) {
        float4 b = *(const float4*)(&Bs[k][cg * 4]);
        float a0 = As[rg * 4 + 0][k];
        float a1 = As[rg * 4 + 1][k];
        float a2 = As[rg * 4 + 2][k];
        float a3 = As[rg * 4 + 3][k];
        acc[0].x = fmaf(a0, b.x, acc[0].x); acc[0].y = fmaf(a0, b.y, acc[0].y);
        acc[0].z = fmaf(a0, b.z, acc[0].z); acc[0].w = fmaf(a0, b.w, acc[0].w);
        acc[1].x = fmaf(a1, b.x, acc[1].x); acc[1].y = fmaf(a1, b.y, acc[1].y);
        acc[1].z = fmaf(a1, b.z, acc[1].z); acc[1].w = fmaf(a1, b.w, acc[1].w);
        acc[2].x = fmaf(a2, b.x, acc[2].x); acc[2].y = fmaf(a2, b.y, acc[2].y);
        acc[2].z = fmaf(a2, b.z, acc[2].z); acc[2].w = fmaf(a2, b.w, acc[2].w);
        acc[3].x = fmaf(a3, b.x, acc[3].x); acc[3].y = fmaf(a3, b.y, acc[3].y);
        acc[3].z = fmaf(a3, b.z, acc[3].z); acc[3].w = fmaf(a3, b.w, acc[3].w);
    }

    const int gcol0 = coltile * 64 + cg * 4;
    if (coltile < 2) {
        float4 vb = *(const float4*)(br + gcol0);
        float4 vb2 = *(const float4*)(bl + gcol0);
#pragma unroll
        for (int i = 0; i < 4; ++i) {
            int row = row0 + rg * 4 + i;
            if (row < N) {
                float4 v = acc[i];
                v.x += vb.x + vb2.x; v.y += vb.y + vb2.y;
                v.z += vb.z + vb2.z; v.w += vb.w + vb2.w;
                *(float4*)(hacc + (size_t)row * DD + gcol0) = v;
            }
        }
    } else {
        const int zc = gcol0 - 128;            // 0..895, multiple of 4
#pragma unroll
        for (int i = 0; i < 4; ++i) {
            int row = row0 + rg * 4 + i;
            if (row < N) {
                ushort4 sv;
                sv.x = f2bf(acc[i].x); sv.y = f2bf(acc[i].y);
                sv.z = f2bf(acc[i].z); sv.w = f2bf(acc[i].w);
                *(ushort4*)(Zb + (size_t)row * (RR * DD) + zc) = sv;
            }
        }
    }
}

// ---------------------------------------------------------------------------
// Counting sort of edges by node_out: histogram -> scan -> scatter.
// ---------------------------------------------------------------------------
__global__ __launch_bounds__(256) void edge_hist(
    const int* __restrict__ node_out, int* __restrict__ cnt, int E)
{
    int e = blockIdx.x * 256 + threadIdx.x;
    if (e < E) atomicAdd(&cnt[node_out[e]], 1);
}

// Single block, 1024 threads. Exclusive scan of cnt[0..N) -> start[0..N].
// Also copies start -> cursor.
__global__ __launch_bounds__(1024) void scan_counts(
    const int* __restrict__ cnt, int* __restrict__ start,
    int* __restrict__ cursor, int N)
{
    __shared__ int part[1024];
    const int t = threadIdx.x;
    const int C = (NN + 1023) / 1024;      // 30
    const int base = t * C;

    int s = 0;
    for (int i = 0; i < C; ++i) {
        int idx = base + i;
        if (idx < N) s += cnt[idx];
    }
    part[t] = s;
    __syncthreads();
    // Hillis-Steele inclusive scan
    for (int off = 1; off < 1024; off <<= 1) {
        int v = 0;
        if (t >= off) v = part[t - off];
        __syncthreads();
        part[t] += v;
        __syncthreads();
    }
    int run = (t == 0) ? 0 : part[t - 1];
    for (int i = 0; i < C; ++i) {
        int idx = base + i;
        if (idx < N) {
            int v = cnt[idx];
            start[idx] = run;
            cursor[idx] = run;
            run += v;
        }
    }
    if (t == 1023) start[N] = run;         // total = E
}

__global__ __launch_bounds__(256) void edge_scatter_sort(
    const int* __restrict__ node_in,
    const int* __restrict__ node_out,
    const int* __restrict__ relation,
    const float* __restrict__ ew,
    int* __restrict__ cursor,
    int* __restrict__ s_zoff,
    float* __restrict__ s_w,
    int E)
{
    int e = blockIdx.x * 256 + threadIdx.x;
    if (e >= E) return;
    int no = node_out[e];
    int pos = atomicAdd(&cursor[no], 1);
    s_zoff[pos] = node_in[e] * (RR * DD) + relation[e] * DD;
    s_w[pos] = ew[e];
}

// ---------------------------------------------------------------------------
// Aggregate: hout[n] = relu(hacc[n] + sum_{e in edges(n)} w_e * Zb[zoff_e])
// One 64-lane wave per node; each lane owns 2 columns (bf16x2 loads).
// No atomics.
// ---------------------------------------------------------------------------
__global__ __launch_bounds__(256) void aggregate(
    const unsigned short* __restrict__ Zb,  // N x 896 bf16
    const int* __restrict__ start,          // N+1
    const int* __restrict__ s_zoff,         // E
    const float* __restrict__ s_w,          // E
    const float* __restrict__ hacc,         // N x 128
    float* __restrict__ hout,               // N x 128
    int N)
{
    int wid = (blockIdx.x * 256 + threadIdx.x) >> 6;   // node index
    int lane = threadIdx.x & 63;
    if (wid >= N) return;

    int e0 = start[wid];
    int e1 = start[wid + 1];

    float accx = 0.f, accy = 0.f;
    for (int e = e0; e < e1; ++e) {
        float wt = s_w[e];
        int off = s_zoff[e] + lane * 2;
        unsigned u = *(const unsigned*)(Zb + off);      // two bf16
        float fx = __uint_as_float(u << 16);
        float fy = __uint_as_float(u & 0xffff0000u);
        accx = fmaf(wt, fx, accx);
        accy = fmaf(wt, fy, accy);
    }

    float2 base = *(const float2*)(hacc + (size_t)wid * DD + lane * 2);
    float2 o;
    o.x = fmaxf(base.x + accx, 0.f);
    o.y = fmaxf(base.y + accy, 0.f);
    *(float2*)(hout + (size_t)wid * DD + lane * 2) = o;
}

// ---------------------------------------------------------------------------
// Graph segment sum: gf[n2g[n]] += nf[n]. node2graph sorted; 32-lane groups
// handle 16 consecutive nodes with per-run local accumulation.
// ---------------------------------------------------------------------------
__global__ __launch_bounds__(256) void graph_sum(
    const float* __restrict__ nf,
    const int* __restrict__ n2g,
    float* __restrict__ gf,
    int N)
{
    int t = blockIdx.x * 256 + threadIdx.x;
    int chunk = t >> 5;
    int lane = t & 31;
    int n0 = chunk * 16;
    if (n0 >= N) return;
    int nend = n0 + 16; if (nend > N) nend = N;

    float4 acc = make_float4(0.f, 0.f, 0.f, 0.f);
    int curg = n2g[n0];
    for (int n = n0; n < nend; ++n) {
        int g = n2g[n];
        if (g != curg) {
            float* dst = gf + (size_t)curg * DD + lane * 4;
            atomicAdd(dst + 0, acc.x); atomicAdd(dst + 1, acc.y);
            atomicAdd(dst + 2, acc.z); atomicAdd(dst + 3, acc.w);
            acc = make_float4(0.f, 0.f, 0.f, 0.f);
            curg = g;
        }
        float4 v = *(const float4*)(nf + (size_t)n * DD + lane * 4);
        acc.x += v.x; acc.y += v.y; acc.z += v.z; acc.w += v.w;
    }
    float* dst = gf + (size_t)curg * DD + lane * 4;
    atomicAdd(dst + 0, acc.x); atomicAdd(dst + 1, acc.y);
    atomicAdd(dst + 2, acc.z); atomicAdd(dst + 3, acc.w);
}

// ---------------------------------------------------------------------------
extern "C" void kernel_launch(void* const* d_in, const int* in_sizes, int n_in,
                              void* d_out, int out_size, void* d_ws, size_t ws_size,
                              hipStream_t stream)
{
    const float* x        = (const float*)d_in[0];
    const int*   node_in  = (const int*)d_in[1];
    const int*   node_out = (const int*)d_in[2];
    const int*   relation = (const int*)d_in[3];
    const float* ew       = (const float*)d_in[4];
    const int*   n2g      = (const int*)d_in[5];
    const float* Wr       = (const float*)d_in[6];
    const float* br       = (const float*)d_in[7];
    const float* Wl       = (const float*)d_in[8];
    const float* bl       = (const float*)d_in[9];

    float* out = (float*)d_out;
    float* gf = out;                 // 16 x 128
    float* nf = out + GG * DD;       // 30000 x 128

    // Workspace layout (~90 MB)
    char* w = (char*)d_ws;
    unsigned short* Zb = (unsigned short*)w;                 w += (size_t)NN * RR * DD * 2;   // 53.76 MB
    float* hacc   = (float*)w;                               w += (size_t)NN * DD * 4;        // 15.36 MB
    float* hbuf   = (float*)w;                               w += (size_t)NN * DD * 4;        // 15.36 MB
    int*   s_zoff = (int*)w;                                 w += (size_t)NE * 4;             // 2.4 MB
    float* s_w    = (float*)w;                               w += (size_t)NE * 4;             // 2.4 MB
    int*   start  = (int*)w;                                 w += (size_t)(NN + 1) * 4 + 60;  // pad
    int*   cursor = (int*)w;                                 w += (size_t)NN * 4 + 64;
    int*   cnt    = (int*)w;                                 w += (size_t)NN * 4 + 64;

    const int N = NN, E = NE;

    // ---- edge sort by destination (once per call, reused by all layers) ----
    hipMemsetAsync(cnt, 0, (size_t)N * sizeof(int), stream);
    edge_hist<<<(E + 255) / 256, 256, 0, stream>>>(node_out, cnt, E);
    scan_counts<<<1, 1024, 0, stream>>>(cnt, start, cursor, N);
    edge_scatter_sort<<<(E + 255) / 256, 256, 0, stream>>>(
        node_in, node_out, relation, ew, cursor, s_zoff, s_w, E);

    // ---- layers ----
    dim3 ggrid((N + 63) / 64, 16);
    const float* hin = x;
    for (int l = 0; l < LL; ++l) {
        const float* Wr_l = Wr + (size_t)l * RR * DD * DD;
        const float* Wl_l = Wl + (size_t)l * DD * DD;
        const float* br_l = br + (size_t)l * DD;
        const float* bl_l = bl + (size_t)l * DD;

        gemm_expand<<<ggrid, 256, 0, stream>>>(hin, Wl_l, Wr_l, br_l, bl_l, hacc, Zb, N);

        float* hout = (l == LL - 1) ? nf : hbuf;
        aggregate<<<(N * 64 + 255) / 256, 256, 0, stream>>>(
            Zb, start, s_zoff, s_w, hacc, hout, N);
        hin = hout;
    }

    // ---- graph_feature ----
    hipMemsetAsync(gf, 0, (size_t)GG * DD * sizeof(float), stream);
    int chunks = (N + 15) / 16;
    graph_sum<<<(chunks * 32 + 255) / 256, 256, 0, stream>>>(nf, n2g, gf, N);
}

// Round 3
// 412.043 us; speedup vs baseline: 8.5589x; 1.9182x over previous
//
#include <hip/hip_runtime.h>

// Problem constants (match reference setup_inputs)
#define NN 30000      // nodes
#define NE 600000     // edges
#define DD 128        // feature dim
#define RR 7          // relations
#define GG 16         // graphs
#define LL 3          // layers

typedef short bf16x8 __attribute__((ext_vector_type(8)));  // 8 bf16 = 4 VGPRs
typedef float f32x4  __attribute__((ext_vector_type(4)));

// ---- bf16 helpers ----------------------------------------------------------
__device__ __forceinline__ unsigned short f2bf(float f) {
    unsigned u = __float_as_uint(f);
    unsigned r = (u + 0x7fffu + ((u >> 16) & 1u)) >> 16;   // round-nearest-even
    return (unsigned short)r;
}

// ---------------------------------------------------------------------------
// Weight pack: Bw[l][n][k] (bf16, n-major) from fp32 Wl (k-major 128x128) and
// Wr (896x128; block r rows r*128..r*128+127, used as B[k][c] -> n=128+r*128+c)
// ---------------------------------------------------------------------------
__global__ __launch_bounds__(256) void pack_weights(
    const float* __restrict__ Wl,   // L x 128 x 128
    const float* __restrict__ Wr,   // L x 896 x 128
    unsigned short* __restrict__ Bw)// L x 1024 x 128
{
    int t = blockIdx.x * 256 + threadIdx.x;
    if (t >= LL * 1024 * DD) return;
    int l = t >> 17;               // / 131072
    int rem = t & 131071;
    int n = rem >> 7;
    int k = rem & 127;
    float v;
    if (n < DD) {
        v = Wl[(size_t)l * DD * DD + k * DD + n];
    } else {
        int q = n - DD;
        v = Wr[(size_t)l * RR * DD * DD + (size_t)((q >> 7) * DD + k) * DD + (q & 127)];
    }
    Bw[(size_t)l * 1024 * DD + n * DD + k] = f2bf(v);
}

// x (fp32) -> bf16
__global__ __launch_bounds__(256) void convert_bf16(
    const float* __restrict__ in, unsigned short* __restrict__ out, int n4)
{
    int i = blockIdx.x * 256 + threadIdx.x;
    if (i >= n4) return;
    float4 v = ((const float4*)in)[i];
    ushort4 o;
    o.x = f2bf(v.x); o.y = f2bf(v.y); o.z = f2bf(v.z); o.w = f2bf(v.w);
    ((ushort4*)out)[i] = o;
}

// ---------------------------------------------------------------------------
// MFMA GEMM: out (N x 1024) = hb (N x 128, bf16) @ B (128 x 1024, bf16)
//   blockIdx.y == 0  -> cols 0..127  -> hacc (fp32, + br + bl)
//   blockIdx.y >= 1  -> cols 128+    -> Zb (bf16)
// Block: 64 rows x 128 cols, 256 threads = 4 waves (wave w: cols w*32..+32).
// Full K=128 staged in LDS. mfma_f32_16x16x32_bf16, layouts per learn_hip m89:
//   A[m=lane&15][k=quad*8+j], B[k=quad*8+j][n=lane&15], D: col=lane&15,
//   row=quad*4+reg.
// LDS stride 136 ushorts = 272 B (16B-aligned, 2-way bank aliasing = free).
// ---------------------------------------------------------------------------
#define ASTR 136
__global__ __launch_bounds__(256) void gemm_mfma(
    const unsigned short* __restrict__ hb,   // N x 128 bf16
    const unsigned short* __restrict__ Bw,   // 1024 x 128 bf16 (n-major)
    const float* __restrict__ br,            // 128
    const float* __restrict__ bl,            // 128
    float* __restrict__ hacc,                // N x 128
    unsigned short* __restrict__ Zb,         // N x 896 bf16
    int N)
{
    __shared__ unsigned short As[64 * ASTR];
    __shared__ unsigned short Bs[128 * ASTR];

    const int tid  = threadIdx.x;
    const int wave = tid >> 6;
    const int lane = tid & 63;
    const int quad = lane >> 4;
    const int l16  = lane & 15;
    const int row0 = blockIdx.x * 64;
    const int col0 = blockIdx.y * 128;       // 0 or 128..896

    // Stage A: 64 rows x 128 k = 1024 16B-chunks, 4 per thread
#pragma unroll
    for (int l = 0; l < 4; ++l) {
        int f = tid + l * 256;               // 0..1023
        int r = f >> 4;
        int c8 = f & 15;
        int row = row0 + r;
        int4 v = make_int4(0, 0, 0, 0);
        if (row < N) v = *(const int4*)(hb + (size_t)row * DD + c8 * 8);
        *(int4*)(As + r * ASTR + c8 * 8) = v;
    }
    // Stage B: 128 n-rows x 128 k = 2048 16B-chunks, 8 per thread
#pragma unroll
    for (int l = 0; l < 8; ++l) {
        int f = tid + l * 256;               // 0..2047
        int n = f >> 4;
        int c8 = f & 15;
        *(int4*)(Bs + n * ASTR + c8 * 8) =
            *(const int4*)(Bw + (size_t)(col0 + n) * DD + c8 * 8);
    }
    __syncthreads();

    f32x4 acc[4][2];
#pragma unroll
    for (int mt = 0; mt < 4; ++mt)
#pragma unroll
        for (int nt = 0; nt < 2; ++nt)
            acc[mt][nt] = (f32x4){0.f, 0.f, 0.f, 0.f};

    const unsigned short* As_l = As + l16 * ASTR;
    const unsigned short* Bs_l = Bs + (wave * 32 + l16) * ASTR;

#pragma unroll
    for (int kc = 0; kc < 4; ++kc) {
        int ko = kc * 32 + quad * 8;
        bf16x8 a0 = *(const bf16x8*)(As_l + 0 * 16 * ASTR + ko);
        bf16x8 a1 = *(const bf16x8*)(As_l + 1 * 16 * ASTR + ko);
        bf16x8 a2 = *(const bf16x8*)(As_l + 2 * 16 * ASTR + ko);
        bf16x8 a3 = *(const bf16x8*)(As_l + 3 * 16 * ASTR + ko);
        bf16x8 b0 = *(const bf16x8*)(Bs_l + 0 * 16 * ASTR + ko);
        bf16x8 b1 = *(const bf16x8*)(Bs_l + 1 * 16 * ASTR + ko);
        acc[0][0] = __builtin_amdgcn_mfma_f32_16x16x32_bf16(a0, b0, acc[0][0], 0, 0, 0);
        acc[1][0] = __builtin_amdgcn_mfma_f32_16x16x32_bf16(a1, b0, acc[1][0], 0, 0, 0);
        acc[2][0] = __builtin_amdgcn_mfma_f32_16x16x32_bf16(a2, b0, acc[2][0], 0, 0, 0);
        acc[3][0] = __builtin_amdgcn_mfma_f32_16x16x32_bf16(a3, b0, acc[3][0], 0, 0, 0);
        acc[0][1] = __builtin_amdgcn_mfma_f32_16x16x32_bf16(a0, b1, acc[0][1], 0, 0, 0);
        acc[1][1] = __builtin_amdgcn_mfma_f32_16x16x32_bf16(a1, b1, acc[1][1], 0, 0, 0);
        acc[2][1] = __builtin_amdgcn_mfma_f32_16x16x32_bf16(a2, b1, acc[2][1], 0, 0, 0);
        acc[3][1] = __builtin_amdgcn_mfma_f32_16x16x32_bf16(a3, b1, acc[3][1], 0, 0, 0);
    }

    const int ncol = wave * 32 + l16;        // 0..127 within tile (nt adds 16)
    if (col0 == 0) {
        float bias0 = br[ncol] + bl[ncol];
        float bias1 = br[ncol + 16] + bl[ncol + 16];
#pragma unroll
        for (int mt = 0; mt < 4; ++mt) {
#pragma unroll
            for (int reg = 0; reg < 4; ++reg) {
                int row = row0 + mt * 16 + quad * 4 + reg;
                if (row < N) {
                    hacc[(size_t)row * DD + ncol]      = acc[mt][0][reg] + bias0;
                    hacc[(size_t)row * DD + ncol + 16] = acc[mt][1][reg] + bias1;
                }
            }
        }
    } else {
        const int zc = col0 - DD + ncol;     // 0..895
#pragma unroll
        for (int mt = 0; mt < 4; ++mt) {
#pragma unroll
            for (int reg = 0; reg < 4; ++reg) {
                int row = row0 + mt * 16 + quad * 4 + reg;
                if (row < N) {
                    Zb[(size_t)row * (RR * DD) + zc]      = f2bf(acc[mt][0][reg]);
                    Zb[(size_t)row * (RR * DD) + zc + 16] = f2bf(acc[mt][1][reg]);
                }
            }
        }
    }
}

// ---------------------------------------------------------------------------
// Counting sort of edges by node_out: histogram -> scan -> scatter.
// ---------------------------------------------------------------------------
__global__ __launch_bounds__(256) void edge_hist(
    const int* __restrict__ node_out, int* __restrict__ cnt, int E)
{
    int e = blockIdx.x * 256 + threadIdx.x;
    if (e < E) atomicAdd(&cnt[node_out[e]], 1);
}

__global__ __launch_bounds__(1024) void scan_counts(
    const int* __restrict__ cnt, int* __restrict__ start,
    int* __restrict__ cursor, int N)
{
    __shared__ int part[1024];
    const int t = threadIdx.x;
    const int C = (NN + 1023) / 1024;      // 30
    const int base = t * C;

    int s = 0;
    for (int i = 0; i < C; ++i) {
        int idx = base + i;
        if (idx < N) s += cnt[idx];
    }
    part[t] = s;
    __syncthreads();
    for (int off = 1; off < 1024; off <<= 1) {
        int v = 0;
        if (t >= off) v = part[t - off];
        __syncthreads();
        part[t] += v;
        __syncthreads();
    }
    int run = (t == 0) ? 0 : part[t - 1];
    for (int i = 0; i < C; ++i) {
        int idx = base + i;
        if (idx < N) {
            int v = cnt[idx];
            start[idx] = run;
            cursor[idx] = run;
            run += v;
        }
    }
    if (t == 1023) start[N] = run;
}

__global__ __launch_bounds__(256) void edge_scatter_sort(
    const int* __restrict__ node_in,
    const int* __restrict__ node_out,
    const int* __restrict__ relation,
    const float* __restrict__ ew,
    int* __restrict__ cursor,
    int2* __restrict__ meta,               // (zoff, weight-bits)
    int E)
{
    int e = blockIdx.x * 256 + threadIdx.x;
    if (e >= E) return;
    int no = node_out[e];
    int pos = atomicAdd(&cursor[no], 1);
    meta[pos] = make_int2(node_in[e] * (RR * DD) + relation[e] * DD,
                          __float_as_int(ew[e]));
}

// ---------------------------------------------------------------------------
// Aggregate: o[n] = relu(hacc[n] + sum_{e in edges(n)} w_e * Zb[zoff_e][:])
// One 64-lane wave per node, each lane owns 2 columns. Edge loop unrolled x4
// for memory-level parallelism. Outputs: fp32 (final layer) or bf16 (next
// layer's GEMM input) — selected by null pointers.
// ---------------------------------------------------------------------------
__global__ __launch_bounds__(256) void aggregate(
    const unsigned short* __restrict__ Zb,  // N x 896 bf16
    const int* __restrict__ start,          // N+1
    const int2* __restrict__ meta,          // E
    const float* __restrict__ hacc,         // N x 128
    float* __restrict__ out_f32,            // N x 128 or null
    unsigned short* __restrict__ out_bf16,  // N x 128 or null
    int N)
{
    int wid = (blockIdx.x * 256 + threadIdx.x) >> 6;
    int lane = threadIdx.x & 63;
    if (wid >= N) return;

    int e0 = start[wid];
    int e1 = start[wid + 1];

    float accx = 0.f, accy = 0.f;
    int e = e0;
    for (; e + 4 <= e1; e += 4) {
        int2 m0 = meta[e + 0];
        int2 m1 = meta[e + 1];
        int2 m2 = meta[e + 2];
        int2 m3 = meta[e + 3];
        unsigned u0 = *(const unsigned*)(Zb + m0.x + lane * 2);
        unsigned u1 = *(const unsigned*)(Zb + m1.x + lane * 2);
        unsigned u2 = *(const unsigned*)(Zb + m2.x + lane * 2);
        unsigned u3 = *(const unsigned*)(Zb + m3.x + lane * 2);
        float w0 = __int_as_float(m0.y), w1 = __int_as_float(m1.y);
        float w2 = __int_as_float(m2.y), w3 = __int_as_float(m3.y);
        accx = fmaf(w0, __uint_as_float(u0 << 16), accx);
        accy = fmaf(w0, __uint_as_float(u0 & 0xffff0000u), accy);
        accx = fmaf(w1, __uint_as_float(u1 << 16), accx);
        accy = fmaf(w1, __uint_as_float(u1 & 0xffff0000u), accy);
        accx = fmaf(w2, __uint_as_float(u2 << 16), accx);
        accy = fmaf(w2, __uint_as_float(u2 & 0xffff0000u), accy);
        accx = fmaf(w3, __uint_as_float(u3 << 16), accx);
        accy = fmaf(w3, __uint_as_float(u3 & 0xffff0000u), accy);
    }
    for (; e < e1; ++e) {
        int2 m = meta[e];
        unsigned u = *(const unsigned*)(Zb + m.x + lane * 2);
        float wt = __int_as_float(m.y);
        accx = fmaf(wt, __uint_as_float(u << 16), accx);
        accy = fmaf(wt, __uint_as_float(u & 0xffff0000u), accy);
    }

    float2 base = *(const float2*)(hacc + (size_t)wid * DD + lane * 2);
    float ox = fmaxf(base.x + accx, 0.f);
    float oy = fmaxf(base.y + accy, 0.f);
    if (out_f32) {
        *(float2*)(out_f32 + (size_t)wid * DD + lane * 2) = make_float2(ox, oy);
    }
    if (out_bf16) {
        ushort2 o; o.x = f2bf(ox); o.y = f2bf(oy);
        *(ushort2*)(out_bf16 + (size_t)wid * DD + lane * 2) = o;
    }
}

// ---------------------------------------------------------------------------
// Graph segment sum: gf[n2g[n]] += nf[n] (n2g sorted).
// ---------------------------------------------------------------------------
__global__ __launch_bounds__(256) void graph_sum(
    const float* __restrict__ nf,
    const int* __restrict__ n2g,
    float* __restrict__ gf,
    int N)
{
    int t = blockIdx.x * 256 + threadIdx.x;
    int chunk = t >> 5;
    int lane = t & 31;
    int n0 = chunk * 16;
    if (n0 >= N) return;
    int nend = n0 + 16; if (nend > N) nend = N;

    float4 acc = make_float4(0.f, 0.f, 0.f, 0.f);
    int curg = n2g[n0];
    for (int n = n0; n < nend; ++n) {
        int g = n2g[n];
        if (g != curg) {
            float* dst = gf + (size_t)curg * DD + lane * 4;
            atomicAdd(dst + 0, acc.x); atomicAdd(dst + 1, acc.y);
            atomicAdd(dst + 2, acc.z); atomicAdd(dst + 3, acc.w);
            acc = make_float4(0.f, 0.f, 0.f, 0.f);
            curg = g;
        }
        float4 v = *(const float4*)(nf + (size_t)n * DD + lane * 4);
        acc.x += v.x; acc.y += v.y; acc.z += v.z; acc.w += v.w;
    }
    float* dst = gf + (size_t)curg * DD + lane * 4;
    atomicAdd(dst + 0, acc.x); atomicAdd(dst + 1, acc.y);
    atomicAdd(dst + 2, acc.z); atomicAdd(dst + 3, acc.w);
}

// ---------------------------------------------------------------------------
extern "C" void kernel_launch(void* const* d_in, const int* in_sizes, int n_in,
                              void* d_out, int out_size, void* d_ws, size_t ws_size,
                              hipStream_t stream)
{
    const float* x        = (const float*)d_in[0];
    const int*   node_in  = (const int*)d_in[1];
    const int*   node_out = (const int*)d_in[2];
    const int*   relation = (const int*)d_in[3];
    const float* ew       = (const float*)d_in[4];
    const int*   n2g      = (const int*)d_in[5];
    const float* Wr       = (const float*)d_in[6];
    const float* br       = (const float*)d_in[7];
    const float* Wl       = (const float*)d_in[8];
    const float* bl       = (const float*)d_in[9];

    float* out = (float*)d_out;
    float* gf = out;                 // 16 x 128
    float* nf = out + GG * DD;       // 30000 x 128

    // Workspace layout (~92 MB)
    char* w = (char*)d_ws;
    unsigned short* Zb  = (unsigned short*)w;  w += (size_t)NN * RR * DD * 2;   // 53.76 MB
    float* hacc         = (float*)w;           w += (size_t)NN * DD * 4;        // 15.36 MB
    unsigned short* hbA = (unsigned short*)w;  w += (size_t)NN * DD * 2;        // 7.68 MB
    unsigned short* hbB = (unsigned short*)w;  w += (size_t)NN * DD * 2;        // 7.68 MB
    unsigned short* Bw  = (unsigned short*)w;  w += (size_t)LL * 1024 * DD * 2; // 0.79 MB
    int2*  meta   = (int2*)w;                  w += (size_t)NE * 8;             // 4.8 MB
    int*   start  = (int*)w;                   w += (size_t)(NN + 1) * 4 + 60;
    int*   cursor = (int*)w;                   w += (size_t)NN * 4 + 64;
    int*   cnt    = (int*)w;                   w += (size_t)NN * 4 + 64;

    const int N = NN, E = NE;

    // ---- once per call: weight pack, x->bf16, edge sort --------------------
    pack_weights<<<(LL * 1024 * DD + 255) / 256, 256, 0, stream>>>(Wl, Wr, Bw);
    convert_bf16<<<(N * DD / 4 + 255) / 256, 256, 0, stream>>>(x, hbA, N * DD / 4);

    hipMemsetAsync(cnt, 0, (size_t)N * sizeof(int), stream);
    edge_hist<<<(E + 255) / 256, 256, 0, stream>>>(node_out, cnt, E);
    scan_counts<<<1, 1024, 0, stream>>>(cnt, start, cursor, N);
    edge_scatter_sort<<<(E + 255) / 256, 256, 0, stream>>>(
        node_in, node_out, relation, ew, cursor, meta, E);

    // ---- layers ----
    dim3 ggrid((N + 63) / 64, 8);
    unsigned short* hin = hbA;
    unsigned short* hnext = hbB;
    for (int l = 0; l < LL; ++l) {
        const float* br_l = br + (size_t)l * DD;
        const float* bl_l = bl + (size_t)l * DD;
        const unsigned short* Bw_l = Bw + (size_t)l * 1024 * DD;

        gemm_mfma<<<ggrid, 256, 0, stream>>>(hin, Bw_l, br_l, bl_l, hacc, Zb, N);

        bool last = (l == LL - 1);
        aggregate<<<(N * 64 + 255) / 256, 256, 0, stream>>>(
            Zb, start, meta, hacc,
            last ? nf : (float*)nullptr,
            last ? (unsigned short*)nullptr : hnext, N);

        unsigned short* t = hin; hin = hnext; hnext = t;
    }

    // ---- graph_feature ----
    hipMemsetAsync(gf, 0, (size_t)GG * DD * sizeof(float), stream);
    int chunks = (N + 15) / 16;
    graph_sum<<<(chunks * 32 + 255) / 256, 256, 0, stream>>>(nf, n2g, gf, N);
}

// Round 4
// 353.276 us; speedup vs baseline: 9.9826x; 1.1663x over previous
//
#include <hip/hip_runtime.h>

// Problem constants (match reference setup_inputs)
#define NN 30000      // nodes
#define NE 600000     // edges
#define DD 128        // feature dim
#define RR 7          // relations
#define GG 16         // graphs
#define LL 3          // layers

typedef short bf16x8 __attribute__((ext_vector_type(8)));  // 8 bf16 = 4 VGPRs
typedef float f32x4  __attribute__((ext_vector_type(4)));

// ---- bf16 helpers ----------------------------------------------------------
__device__ __forceinline__ unsigned short f2bf(float f) {
    unsigned u = __float_as_uint(f);
    unsigned r = (u + 0x7fffu + ((u >> 16) & 1u)) >> 16;   // round-nearest-even
    return (unsigned short)r;
}

// ---------------------------------------------------------------------------
// Weight pack: Bw[l][n][k] (bf16, n-major) from fp32 Wl (k-major 128x128) and
// Wr (896x128; block r rows r*128..r*128+127, used as B[k][c] -> n=128+r*128+c)
// ---------------------------------------------------------------------------
__global__ __launch_bounds__(256) void pack_weights(
    const float* __restrict__ Wl,   // L x 128 x 128
    const float* __restrict__ Wr,   // L x 896 x 128
    unsigned short* __restrict__ Bw)// L x 1024 x 128
{
    int t = blockIdx.x * 256 + threadIdx.x;
    if (t >= LL * 1024 * DD) return;
    int l = t >> 17;               // / 131072
    int rem = t & 131071;
    int n = rem >> 7;
    int k = rem & 127;
    float v;
    if (n < DD) {
        v = Wl[(size_t)l * DD * DD + k * DD + n];
    } else {
        int q = n - DD;
        v = Wr[(size_t)l * RR * DD * DD + (size_t)((q >> 7) * DD + k) * DD + (q & 127)];
    }
    Bw[(size_t)l * 1024 * DD + n * DD + k] = f2bf(v);
}

// x (fp32) -> bf16
__global__ __launch_bounds__(256) void convert_bf16(
    const float* __restrict__ in, unsigned short* __restrict__ out, int n4)
{
    int i = blockIdx.x * 256 + threadIdx.x;
    if (i >= n4) return;
    float4 v = ((const float4*)in)[i];
    ushort4 o;
    o.x = f2bf(v.x); o.y = f2bf(v.y); o.z = f2bf(v.z); o.w = f2bf(v.w);
    ((ushort4*)out)[i] = o;
}

// ---------------------------------------------------------------------------
// MFMA GEMM: out (N x 1024) = hb (N x 128, bf16) @ B (128 x 1024, bf16)
//   blockIdx.y == 0  -> cols 0..127  -> hacc (fp32, + br + bl)
//   blockIdx.y >= 1  -> cols 128+    -> Zb (bf16)
// Block: 64 rows x 128 cols, 256 threads = 4 waves (wave w: cols w*32..+32).
// Full K=128 staged in LDS. mfma_f32_16x16x32_bf16 (layouts: learn_hip m89).
// LDS stride 136 ushorts = 272 B (16B-aligned, 2-way bank aliasing = free).
// ---------------------------------------------------------------------------
#define ASTR 136
__global__ __launch_bounds__(256) void gemm_mfma(
    const unsigned short* __restrict__ hb,   // N x 128 bf16
    const unsigned short* __restrict__ Bw,   // 1024 x 128 bf16 (n-major)
    const float* __restrict__ br,            // 128
    const float* __restrict__ bl,            // 128
    float* __restrict__ hacc,                // N x 128
    unsigned short* __restrict__ Zb,         // N x 896 bf16
    int N)
{
    __shared__ unsigned short As[64 * ASTR];
    __shared__ unsigned short Bs[128 * ASTR];

    const int tid  = threadIdx.x;
    const int wave = tid >> 6;
    const int lane = tid & 63;
    const int quad = lane >> 4;
    const int l16  = lane & 15;
    const int row0 = blockIdx.x * 64;
    const int col0 = blockIdx.y * 128;       // 0 or 128..896

#pragma unroll
    for (int l = 0; l < 4; ++l) {
        int f = tid + l * 256;               // 0..1023
        int r = f >> 4;
        int c8 = f & 15;
        int row = row0 + r;
        int4 v = make_int4(0, 0, 0, 0);
        if (row < N) v = *(const int4*)(hb + (size_t)row * DD + c8 * 8);
        *(int4*)(As + r * ASTR + c8 * 8) = v;
    }
#pragma unroll
    for (int l = 0; l < 8; ++l) {
        int f = tid + l * 256;               // 0..2047
        int n = f >> 4;
        int c8 = f & 15;
        *(int4*)(Bs + n * ASTR + c8 * 8) =
            *(const int4*)(Bw + (size_t)(col0 + n) * DD + c8 * 8);
    }
    __syncthreads();

    f32x4 acc[4][2];
#pragma unroll
    for (int mt = 0; mt < 4; ++mt)
#pragma unroll
        for (int nt = 0; nt < 2; ++nt)
            acc[mt][nt] = (f32x4){0.f, 0.f, 0.f, 0.f};

    const unsigned short* As_l = As + l16 * ASTR;
    const unsigned short* Bs_l = Bs + (wave * 32 + l16) * ASTR;

#pragma unroll
    for (int kc = 0; kc < 4; ++kc) {
        int ko = kc * 32 + quad * 8;
        bf16x8 a0 = *(const bf16x8*)(As_l + 0 * 16 * ASTR + ko);
        bf16x8 a1 = *(const bf16x8*)(As_l + 1 * 16 * ASTR + ko);
        bf16x8 a2 = *(const bf16x8*)(As_l + 2 * 16 * ASTR + ko);
        bf16x8 a3 = *(const bf16x8*)(As_l + 3 * 16 * ASTR + ko);
        bf16x8 b0 = *(const bf16x8*)(Bs_l + 0 * 16 * ASTR + ko);
        bf16x8 b1 = *(const bf16x8*)(Bs_l + 1 * 16 * ASTR + ko);
        acc[0][0] = __builtin_amdgcn_mfma_f32_16x16x32_bf16(a0, b0, acc[0][0], 0, 0, 0);
        acc[1][0] = __builtin_amdgcn_mfma_f32_16x16x32_bf16(a1, b0, acc[1][0], 0, 0, 0);
        acc[2][0] = __builtin_amdgcn_mfma_f32_16x16x32_bf16(a2, b0, acc[2][0], 0, 0, 0);
        acc[3][0] = __builtin_amdgcn_mfma_f32_16x16x32_bf16(a3, b0, acc[3][0], 0, 0, 0);
        acc[0][1] = __builtin_amdgcn_mfma_f32_16x16x32_bf16(a0, b1, acc[0][1], 0, 0, 0);
        acc[1][1] = __builtin_amdgcn_mfma_f32_16x16x32_bf16(a1, b1, acc[1][1], 0, 0, 0);
        acc[2][1] = __builtin_amdgcn_mfma_f32_16x16x32_bf16(a2, b1, acc[2][1], 0, 0, 0);
        acc[3][1] = __builtin_amdgcn_mfma_f32_16x16x32_bf16(a3, b1, acc[3][1], 0, 0, 0);
    }

    const int ncol = wave * 32 + l16;
    if (col0 == 0) {
        float bias0 = br[ncol] + bl[ncol];
        float bias1 = br[ncol + 16] + bl[ncol + 16];
#pragma unroll
        for (int mt = 0; mt < 4; ++mt) {
#pragma unroll
            for (int reg = 0; reg < 4; ++reg) {
                int row = row0 + mt * 16 + quad * 4 + reg;
                if (row < N) {
                    hacc[(size_t)row * DD + ncol]      = acc[mt][0][reg] + bias0;
                    hacc[(size_t)row * DD + ncol + 16] = acc[mt][1][reg] + bias1;
                }
            }
        }
    } else {
        const int zc = col0 - DD + ncol;
#pragma unroll
        for (int mt = 0; mt < 4; ++mt) {
#pragma unroll
            for (int reg = 0; reg < 4; ++reg) {
                int row = row0 + mt * 16 + quad * 4 + reg;
                if (row < N) {
                    Zb[(size_t)row * (RR * DD) + zc]      = f2bf(acc[mt][0][reg]);
                    Zb[(size_t)row * (RR * DD) + zc + 16] = f2bf(acc[mt][1][reg]);
                }
            }
        }
    }
}

// ---------------------------------------------------------------------------
// Counting sort of edges by node_out: histogram -> parallel scan -> scatter.
// ---------------------------------------------------------------------------
__global__ __launch_bounds__(256) void edge_hist(
    const int* __restrict__ node_out, int* __restrict__ cnt, int E)
{
    int e = blockIdx.x * 256 + threadIdx.x;
    if (e < E) atomicAdd(&cnt[node_out[e]], 1);
}

// Pass 1: per-block (256-wide) exclusive scan + block sum. 118 blocks.
__global__ __launch_bounds__(256) void scan_blk(
    const int* __restrict__ cnt, int* __restrict__ lscan,
    int* __restrict__ bsum, int N)
{
    __shared__ int s[256];
    int t = threadIdx.x;
    int i = blockIdx.x * 256 + t;
    int v = (i < N) ? cnt[i] : 0;
    s[t] = v;
    __syncthreads();
#pragma unroll
    for (int off = 1; off < 256; off <<= 1) {
        int u = (t >= off) ? s[t - off] : 0;
        __syncthreads();
        s[t] += u;
        __syncthreads();
    }
    if (i < N) lscan[i] = s[t] - v;          // exclusive
    if (t == 255) bsum[blockIdx.x] = s[255];
}

// Pass 2: single small block scans the 118 block sums (exclusive).
__global__ __launch_bounds__(128) void scan_bsum(
    int* __restrict__ bsum, int* __restrict__ boff, int nb)
{
    __shared__ int s[128];
    int t = threadIdx.x;
    int v = (t < nb) ? bsum[t] : 0;
    s[t] = v;
    __syncthreads();
#pragma unroll
    for (int off = 1; off < 128; off <<= 1) {
        int u = (t >= off) ? s[t - off] : 0;
        __syncthreads();
        s[t] += u;
        __syncthreads();
    }
    if (t < nb) boff[t] = s[t] - v;          // exclusive
}

// Pass 3: start[i] = lscan[i] + boff[block]; cursor copy; start[N] = E.
__global__ __launch_bounds__(256) void scan_add(
    const int* __restrict__ lscan, const int* __restrict__ boff,
    int* __restrict__ start, int* __restrict__ cursor, int N)
{
    int i = blockIdx.x * 256 + threadIdx.x;
    if (i < N) {
        int v = lscan[i] + boff[i >> 8];
        start[i] = v;
        cursor[i] = v;
    }
    if (i == N) start[N] = NE;
}

__global__ __launch_bounds__(256) void edge_scatter_sort(
    const int* __restrict__ node_in,
    const int* __restrict__ node_out,
    const int* __restrict__ relation,
    const float* __restrict__ ew,
    int* __restrict__ cursor,
    int2* __restrict__ meta,               // (zoff, weight-bits)
    int E)
{
    int e = blockIdx.x * 256 + threadIdx.x;
    if (e >= E) return;
    int no = node_out[e];
    int pos = atomicAdd(&cursor[no], 1);
    meta[pos] = make_int2(node_in[e] * (RR * DD) + relation[e] * DD,
                          __float_as_int(ew[e]));
}

// ---------------------------------------------------------------------------
// Aggregate: o[n] = relu(hacc[n] + sum_{e in edges(n)} w_e * Zb[zoff_e][:])
// One 64-lane wave per node, each lane owns 2 columns. Edge loop unrolled x4.
// ---------------------------------------------------------------------------
__global__ __launch_bounds__(256) void aggregate(
    const unsigned short* __restrict__ Zb,  // N x 896 bf16
    const int* __restrict__ start,          // N+1
    const int2* __restrict__ meta,          // E
    const float* __restrict__ hacc,         // N x 128
    float* __restrict__ out_f32,            // N x 128 or null
    unsigned short* __restrict__ out_bf16,  // N x 128 or null
    int N)
{
    int wid = (blockIdx.x * 256 + threadIdx.x) >> 6;
    int lane = threadIdx.x & 63;
    if (wid >= N) return;

    int e0 = start[wid];
    int e1 = start[wid + 1];

    float accx = 0.f, accy = 0.f;
    int e = e0;
    for (; e + 4 <= e1; e += 4) {
        int2 m0 = meta[e + 0];
        int2 m1 = meta[e + 1];
        int2 m2 = meta[e + 2];
        int2 m3 = meta[e + 3];
        unsigned u0 = *(const unsigned*)(Zb + m0.x + lane * 2);
        unsigned u1 = *(const unsigned*)(Zb + m1.x + lane * 2);
        unsigned u2 = *(const unsigned*)(Zb + m2.x + lane * 2);
        unsigned u3 = *(const unsigned*)(Zb + m3.x + lane * 2);
        float w0 = __int_as_float(m0.y), w1 = __int_as_float(m1.y);
        float w2 = __int_as_float(m2.y), w3 = __int_as_float(m3.y);
        accx = fmaf(w0, __uint_as_float(u0 << 16), accx);
        accy = fmaf(w0, __uint_as_float(u0 & 0xffff0000u), accy);
        accx = fmaf(w1, __uint_as_float(u1 << 16), accx);
        accy = fmaf(w1, __uint_as_float(u1 & 0xffff0000u), accy);
        accx = fmaf(w2, __uint_as_float(u2 << 16), accx);
        accy = fmaf(w2, __uint_as_float(u2 & 0xffff0000u), accy);
        accx = fmaf(w3, __uint_as_float(u3 << 16), accx);
        accy = fmaf(w3, __uint_as_float(u3 & 0xffff0000u), accy);
    }
    for (; e < e1; ++e) {
        int2 m = meta[e];
        unsigned u = *(const unsigned*)(Zb + m.x + lane * 2);
        float wt = __int_as_float(m.y);
        accx = fmaf(wt, __uint_as_float(u << 16), accx);
        accy = fmaf(wt, __uint_as_float(u & 0xffff0000u), accy);
    }

    float2 base = *(const float2*)(hacc + (size_t)wid * DD + lane * 2);
    float ox = fmaxf(base.x + accx, 0.f);
    float oy = fmaxf(base.y + accy, 0.f);
    if (out_f32) {
        *(float2*)(out_f32 + (size_t)wid * DD + lane * 2) = make_float2(ox, oy);
    }
    if (out_bf16) {
        ushort2 o; o.x = f2bf(ox); o.y = f2bf(oy);
        *(ushort2*)(out_bf16 + (size_t)wid * DD + lane * 2) = o;
    }
}

// ---------------------------------------------------------------------------
// Graph segment sum: gf[n2g[n]] += nf[n] (n2g sorted).
// ---------------------------------------------------------------------------
__global__ __launch_bounds__(256) void graph_sum(
    const float* __restrict__ nf,
    const int* __restrict__ n2g,
    float* __restrict__ gf,
    int N)
{
    int t = blockIdx.x * 256 + threadIdx.x;
    int chunk = t >> 5;
    int lane = t & 31;
    int n0 = chunk * 16;
    if (n0 >= N) return;
    int nend = n0 + 16; if (nend > N) nend = N;

    float4 acc = make_float4(0.f, 0.f, 0.f, 0.f);
    int curg = n2g[n0];
    for (int n = n0; n < nend; ++n) {
        int g = n2g[n];
        if (g != curg) {
            float* dst = gf + (size_t)curg * DD + lane * 4;
            atomicAdd(dst + 0, acc.x); atomicAdd(dst + 1, acc.y);
            atomicAdd(dst + 2, acc.z); atomicAdd(dst + 3, acc.w);
            acc = make_float4(0.f, 0.f, 0.f, 0.f);
            curg = g;
        }
        float4 v = *(const float4*)(nf + (size_t)n * DD + lane * 4);
        acc.x += v.x; acc.y += v.y; acc.z += v.z; acc.w += v.w;
    }
    float* dst = gf + (size_t)curg * DD + lane * 4;
    atomicAdd(dst + 0, acc.x); atomicAdd(dst + 1, acc.y);
    atomicAdd(dst + 2, acc.z); atomicAdd(dst + 3, acc.w);
}

// ---------------------------------------------------------------------------
extern "C" void kernel_launch(void* const* d_in, const int* in_sizes, int n_in,
                              void* d_out, int out_size, void* d_ws, size_t ws_size,
                              hipStream_t stream)
{
    const float* x        = (const float*)d_in[0];
    const int*   node_in  = (const int*)d_in[1];
    const int*   node_out = (const int*)d_in[2];
    const int*   relation = (const int*)d_in[3];
    const float* ew       = (const float*)d_in[4];
    const int*   n2g      = (const int*)d_in[5];
    const float* Wr       = (const float*)d_in[6];
    const float* br       = (const float*)d_in[7];
    const float* Wl       = (const float*)d_in[8];
    const float* bl       = (const float*)d_in[9];

    float* out = (float*)d_out;
    float* gf = out;                 // 16 x 128
    float* nf = out + GG * DD;       // 30000 x 128

    // Workspace layout (~92 MB)
    char* w = (char*)d_ws;
    unsigned short* Zb  = (unsigned short*)w;  w += (size_t)NN * RR * DD * 2;   // 53.76 MB
    float* hacc         = (float*)w;           w += (size_t)NN * DD * 4;        // 15.36 MB
    unsigned short* hbA = (unsigned short*)w;  w += (size_t)NN * DD * 2;        // 7.68 MB
    unsigned short* hbB = (unsigned short*)w;  w += (size_t)NN * DD * 2;        // 7.68 MB
    unsigned short* Bw  = (unsigned short*)w;  w += (size_t)LL * 1024 * DD * 2; // 0.79 MB
    int2*  meta   = (int2*)w;                  w += (size_t)NE * 8;             // 4.8 MB
    int*   start  = (int*)w;                   w += (size_t)(NN + 1) * 4 + 60;
    int*   cursor = (int*)w;                   w += (size_t)NN * 4 + 64;
    int*   cnt    = (int*)w;                   w += (size_t)NN * 4 + 64;
    int*   lscan  = (int*)w;                   w += (size_t)NN * 4 + 64;
    int*   bsum   = (int*)w;                   w += 256 * 4;
    int*   boff   = (int*)w;                   w += 256 * 4;

    const int N = NN, E = NE;
    const int NB = (N + 255) / 256;            // 118

    // ---- once per call: weight pack, x->bf16, edge sort --------------------
    pack_weights<<<(LL * 1024 * DD + 255) / 256, 256, 0, stream>>>(Wl, Wr, Bw);
    convert_bf16<<<(N * DD / 4 + 255) / 256, 256, 0, stream>>>(x, hbA, N * DD / 4);

    hipMemsetAsync(cnt, 0, (size_t)N * sizeof(int), stream);
    edge_hist<<<(E + 255) / 256, 256, 0, stream>>>(node_out, cnt, E);
    scan_blk<<<NB, 256, 0, stream>>>(cnt, lscan, bsum, N);
    scan_bsum<<<1, 128, 0, stream>>>(bsum, boff, NB);
    scan_add<<<(N + 256) / 256, 256, 0, stream>>>(lscan, boff, start, cursor, N);
    edge_scatter_sort<<<(E + 255) / 256, 256, 0, stream>>>(
        node_in, node_out, relation, ew, cursor, meta, E);

    // ---- layers ----
    dim3 ggrid((N + 63) / 64, 8);
    unsigned short* hin = hbA;
    unsigned short* hnext = hbB;
    for (int l = 0; l < LL; ++l) {
        const float* br_l = br + (size_t)l * DD;
        const float* bl_l = bl + (size_t)l * DD;
        const unsigned short* Bw_l = Bw + (size_t)l * 1024 * DD;

        gemm_mfma<<<ggrid, 256, 0, stream>>>(hin, Bw_l, br_l, bl_l, hacc, Zb, N);

        bool last = (l == LL - 1);
        aggregate<<<(N * 64 + 255) / 256, 256, 0, stream>>>(
            Zb, start, meta, hacc,
            last ? nf : (float*)nullptr,
            last ? (unsigned short*)nullptr : hnext, N);

        unsigned short* t = hin; hin = hnext; hnext = t;
    }

    // ---- graph_feature ----
    hipMemsetAsync(gf, 0, (size_t)GG * DD * sizeof(float), stream);
    int chunks = (N + 15) / 16;
    graph_sum<<<(chunks * 32 + 255) / 256, 256, 0, stream>>>(nf, n2g, gf, N);
}

// Round 5
// 346.288 us; speedup vs baseline: 10.1841x; 1.0202x over previous
//
#include <hip/hip_runtime.h>

// Problem constants (match reference setup_inputs)
#define NN 30000      // nodes
#define NE 600000     // edges
#define DD 128        // feature dim
#define RR 7          // relations
#define GG 16         // graphs
#define LL 3          // layers

typedef short bf16x8 __attribute__((ext_vector_type(8)));  // 8 bf16 = 4 VGPRs
typedef float f32x4  __attribute__((ext_vector_type(4)));

// ---- bf16 helpers ----------------------------------------------------------
__device__ __forceinline__ unsigned short f2bf(float f) {
    unsigned u = __float_as_uint(f);
    unsigned r = (u + 0x7fffu + ((u >> 16) & 1u)) >> 16;   // round-nearest-even
    return (unsigned short)r;
}
__device__ __forceinline__ float bf2f(unsigned short b) {
    return __uint_as_float(((unsigned)b) << 16);
}

// async global->LDS, 16B per lane; LDS dest = wave-uniform base + lane*16
__device__ __forceinline__ void gl_lds16(const void* g, void* l) {
    __builtin_amdgcn_global_load_lds(
        (const __attribute__((address_space(1))) void*)g,
        (__attribute__((address_space(3))) void*)l, 16, 0, 0);
}

// ---------------------------------------------------------------------------
// Weight pack: Bw[l][n][k] (bf16, n-major) from fp32 Wl (k-major 128x128) and
// Wr (896x128; block r rows, B[k][c] -> n=128+r*128+c)
// ---------------------------------------------------------------------------
__global__ __launch_bounds__(256) void pack_weights(
    const float* __restrict__ Wl,   // L x 128 x 128
    const float* __restrict__ Wr,   // L x 896 x 128
    unsigned short* __restrict__ Bw)// L x 1024 x 128
{
    int t = blockIdx.x * 256 + threadIdx.x;
    if (t >= LL * 1024 * DD) return;
    int l = t >> 17;
    int rem = t & 131071;
    int n = rem >> 7;
    int k = rem & 127;
    float v;
    if (n < DD) {
        v = Wl[(size_t)l * DD * DD + k * DD + n];
    } else {
        int q = n - DD;
        v = Wr[(size_t)l * RR * DD * DD + (size_t)((q >> 7) * DD + k) * DD + (q & 127)];
    }
    Bw[(size_t)l * 1024 * DD + n * DD + k] = f2bf(v);
}

// x (fp32) -> bf16
__global__ __launch_bounds__(256) void convert_bf16(
    const float* __restrict__ in, unsigned short* __restrict__ out, int n4)
{
    int i = blockIdx.x * 256 + threadIdx.x;
    if (i >= n4) return;
    float4 v = ((const float4*)in)[i];
    ushort4 o;
    o.x = f2bf(v.x); o.y = f2bf(v.y); o.z = f2bf(v.z); o.w = f2bf(v.w);
    ((ushort4*)out)[i] = o;
}

// ---------------------------------------------------------------------------
// MFMA GEMM: out (N x 1024) = hb (N x 128, bf16) @ B (128 x 1024, bf16)
//   blockIdx.y == 0  -> cols 0..127  -> haccb (bf16, + br + bl)
//   blockIdx.y >= 1  -> cols 128+    -> Zb (bf16)
// Block: 64 rows x 128 cols, 256 threads = 4 waves. Full K=128 in LDS via
// global_load_lds width=16 (A: 4 rows/issue, B tile contiguous 32 KB in Bw).
// ASTR=128 (no pad) — required by global_load_lds lane ordering; bank pattern
// identical to learn_hip m97 (acceptable).
// ---------------------------------------------------------------------------
#define ASTR 128
__global__ __launch_bounds__(256) void gemm_mfma(
    const unsigned short* __restrict__ hb,   // N x 128 bf16
    const unsigned short* __restrict__ Bw,   // 1024 x 128 bf16 (n-major)
    const float* __restrict__ br,            // 128
    const float* __restrict__ bl,            // 128
    unsigned short* __restrict__ haccb,      // N x 128 bf16
    unsigned short* __restrict__ Zb,         // N x 896 bf16
    int N)
{
    __shared__ unsigned short As[64 * ASTR];   // 16 KB
    __shared__ unsigned short Bs[128 * ASTR];  // 32 KB

    const int tid  = threadIdx.x;
    const int wave = tid >> 6;
    const int lane = tid & 63;
    const int quad = lane >> 4;
    const int l16  = lane & 15;
    const int row0 = blockIdx.x * 64;
    const int col0 = blockIdx.y * 128;       // 0 or 128..896

    // A: 64 rows x 128 ushort = 16 KB = 16 wave-issues of 1 KB (4 rows each).
    // NOTE: last block reads up to 16 rows past N; hb sits mid-workspace so
    // the overrun is safe, and garbage rows only affect masked-out outputs.
#pragma unroll
    for (int i = 0; i < 4; ++i) {
        int g = i * 4 + wave;                // 0..15
        gl_lds16(hb + (size_t)(row0 + g * 4) * DD + lane * 8,
                 As + g * 512);
    }
    // B: 128x128 tile contiguous 32 KB in Bw -> 32 wave-issues.
#pragma unroll
    for (int i = 0; i < 8; ++i) {
        int g = i * 4 + wave;                // 0..31
        gl_lds16(Bw + (size_t)col0 * DD + (size_t)g * 512 + lane * 8,
                 Bs + g * 512);
    }
    __syncthreads();

    f32x4 acc[4][2];
#pragma unroll
    for (int mt = 0; mt < 4; ++mt)
#pragma unroll
        for (int nt = 0; nt < 2; ++nt)
            acc[mt][nt] = (f32x4){0.f, 0.f, 0.f, 0.f};

    const unsigned short* As_l = As + l16 * ASTR;
    const unsigned short* Bs_l = Bs + (wave * 32 + l16) * ASTR;

#pragma unroll
    for (int kc = 0; kc < 4; ++kc) {
        int ko = kc * 32 + quad * 8;
        bf16x8 a0 = *(const bf16x8*)(As_l + 0 * 16 * ASTR + ko);
        bf16x8 a1 = *(const bf16x8*)(As_l + 1 * 16 * ASTR + ko);
        bf16x8 a2 = *(const bf16x8*)(As_l + 2 * 16 * ASTR + ko);
        bf16x8 a3 = *(const bf16x8*)(As_l + 3 * 16 * ASTR + ko);
        bf16x8 b0 = *(const bf16x8*)(Bs_l + 0 * 16 * ASTR + ko);
        bf16x8 b1 = *(const bf16x8*)(Bs_l + 1 * 16 * ASTR + ko);
        acc[0][0] = __builtin_amdgcn_mfma_f32_16x16x32_bf16(a0, b0, acc[0][0], 0, 0, 0);
        acc[1][0] = __builtin_amdgcn_mfma_f32_16x16x32_bf16(a1, b0, acc[1][0], 0, 0, 0);
        acc[2][0] = __builtin_amdgcn_mfma_f32_16x16x32_bf16(a2, b0, acc[2][0], 0, 0, 0);
        acc[3][0] = __builtin_amdgcn_mfma_f32_16x16x32_bf16(a3, b0, acc[3][0], 0, 0, 0);
        acc[0][1] = __builtin_amdgcn_mfma_f32_16x16x32_bf16(a0, b1, acc[0][1], 0, 0, 0);
        acc[1][1] = __builtin_amdgcn_mfma_f32_16x16x32_bf16(a1, b1, acc[1][1], 0, 0, 0);
        acc[2][1] = __builtin_amdgcn_mfma_f32_16x16x32_bf16(a2, b1, acc[2][1], 0, 0, 0);
        acc[3][1] = __builtin_amdgcn_mfma_f32_16x16x32_bf16(a3, b1, acc[3][1], 0, 0, 0);
    }

    const int ncol = wave * 32 + l16;
    if (col0 == 0) {
        float bias0 = br[ncol] + bl[ncol];
        float bias1 = br[ncol + 16] + bl[ncol + 16];
#pragma unroll
        for (int mt = 0; mt < 4; ++mt) {
#pragma unroll
            for (int reg = 0; reg < 4; ++reg) {
                int row = row0 + mt * 16 + quad * 4 + reg;
                if (row < N) {
                    haccb[(size_t)row * DD + ncol]      = f2bf(acc[mt][0][reg] + bias0);
                    haccb[(size_t)row * DD + ncol + 16] = f2bf(acc[mt][1][reg] + bias1);
                }
            }
        }
    } else {
        const int zc = col0 - DD + ncol;
#pragma unroll
        for (int mt = 0; mt < 4; ++mt) {
#pragma unroll
            for (int reg = 0; reg < 4; ++reg) {
                int row = row0 + mt * 16 + quad * 4 + reg;
                if (row < N) {
                    Zb[(size_t)row * (RR * DD) + zc]      = f2bf(acc[mt][0][reg]);
                    Zb[(size_t)row * (RR * DD) + zc + 16] = f2bf(acc[mt][1][reg]);
                }
            }
        }
    }
}

// ---------------------------------------------------------------------------
// Counting sort of edges by node_out: histogram -> parallel scan -> scatter.
// ---------------------------------------------------------------------------
__global__ __launch_bounds__(256) void edge_hist(
    const int* __restrict__ node_out, int* __restrict__ cnt, int E)
{
    int e = blockIdx.x * 256 + threadIdx.x;
    if (e < E) atomicAdd(&cnt[node_out[e]], 1);
}

__global__ __launch_bounds__(256) void scan_blk(
    const int* __restrict__ cnt, int* __restrict__ lscan,
    int* __restrict__ bsum, int N)
{
    __shared__ int s[256];
    int t = threadIdx.x;
    int i = blockIdx.x * 256 + t;
    int v = (i < N) ? cnt[i] : 0;
    s[t] = v;
    __syncthreads();
#pragma unroll
    for (int off = 1; off < 256; off <<= 1) {
        int u = (t >= off) ? s[t - off] : 0;
        __syncthreads();
        s[t] += u;
        __syncthreads();
    }
    if (i < N) lscan[i] = s[t] - v;
    if (t == 255) bsum[blockIdx.x] = s[255];
}

__global__ __launch_bounds__(128) void scan_bsum(
    int* __restrict__ bsum, int* __restrict__ boff, int nb)
{
    __shared__ int s[128];
    int t = threadIdx.x;
    int v = (t < nb) ? bsum[t] : 0;
    s[t] = v;
    __syncthreads();
#pragma unroll
    for (int off = 1; off < 128; off <<= 1) {
        int u = (t >= off) ? s[t - off] : 0;
        __syncthreads();
        s[t] += u;
        __syncthreads();
    }
    if (t < nb) boff[t] = s[t] - v;
}

__global__ __launch_bounds__(256) void scan_add(
    const int* __restrict__ lscan, const int* __restrict__ boff,
    int* __restrict__ start, int* __restrict__ cursor, int N)
{
    int i = blockIdx.x * 256 + threadIdx.x;
    if (i < N) {
        int v = lscan[i] + boff[i >> 8];
        start[i] = v;
        cursor[i] = v;
    }
    if (i == N) start[N] = NE;
}

__global__ __launch_bounds__(256) void edge_scatter_sort(
    const int* __restrict__ node_in,
    const int* __restrict__ node_out,
    const int* __restrict__ relation,
    const float* __restrict__ ew,
    int* __restrict__ cursor,
    int2* __restrict__ meta,               // (zoff, weight-bits)
    int E)
{
    int e = blockIdx.x * 256 + threadIdx.x;
    if (e >= E) return;
    int no = node_out[e];
    int pos = atomicAdd(&cursor[no], 1);
    meta[pos] = make_int2(node_in[e] * (RR * DD) + relation[e] * DD,
                          __float_as_int(ew[e]));
}

// ---------------------------------------------------------------------------
// Aggregate: o[n] = relu(haccb[n] + sum_{e in edges(n)} w_e * Zb[zoff_e][:])
// One 64-lane wave per node, lane owns 2 columns. Edge loop unrolled x8 for
// memory-level parallelism (gathers are the latency chain).
// ---------------------------------------------------------------------------
__global__ __launch_bounds__(256) void aggregate(
    const unsigned short* __restrict__ Zb,  // N x 896 bf16
    const int* __restrict__ start,          // N+1
    const int2* __restrict__ meta,          // E
    const unsigned short* __restrict__ haccb, // N x 128 bf16
    float* __restrict__ out_f32,            // N x 128 or null
    unsigned short* __restrict__ out_bf16,  // N x 128 or null
    int N)
{
    int wid = (blockIdx.x * 256 + threadIdx.x) >> 6;
    int lane = threadIdx.x & 63;
    if (wid >= N) return;

    int e0 = start[wid];
    int e1 = start[wid + 1];

    float accx = 0.f, accy = 0.f;
    int e = e0;
    for (; e + 8 <= e1; e += 8) {
        unsigned u[8]; float wt[8];
#pragma unroll
        for (int j = 0; j < 8; ++j) {
            int2 m = meta[e + j];
            u[j] = *(const unsigned*)(Zb + m.x + lane * 2);
            wt[j] = __int_as_float(m.y);
        }
#pragma unroll
        for (int j = 0; j < 8; ++j) {
            accx = fmaf(wt[j], __uint_as_float(u[j] << 16), accx);
            accy = fmaf(wt[j], __uint_as_float(u[j] & 0xffff0000u), accy);
        }
    }
    for (; e + 2 <= e1; e += 2) {
        int2 m0 = meta[e];
        int2 m1 = meta[e + 1];
        unsigned u0 = *(const unsigned*)(Zb + m0.x + lane * 2);
        unsigned u1 = *(const unsigned*)(Zb + m1.x + lane * 2);
        float w0 = __int_as_float(m0.y), w1 = __int_as_float(m1.y);
        accx = fmaf(w0, __uint_as_float(u0 << 16), accx);
        accy = fmaf(w0, __uint_as_float(u0 & 0xffff0000u), accy);
        accx = fmaf(w1, __uint_as_float(u1 << 16), accx);
        accy = fmaf(w1, __uint_as_float(u1 & 0xffff0000u), accy);
    }
    if (e < e1) {
        int2 m = meta[e];
        unsigned u = *(const unsigned*)(Zb + m.x + lane * 2);
        float wt = __int_as_float(m.y);
        accx = fmaf(wt, __uint_as_float(u << 16), accx);
        accy = fmaf(wt, __uint_as_float(u & 0xffff0000u), accy);
    }

    unsigned bu = *(const unsigned*)(haccb + (size_t)wid * DD + lane * 2);
    float ox = fmaxf(bf2f((unsigned short)(bu & 0xffffu)) + accx, 0.f);
    float oy = fmaxf(bf2f((unsigned short)(bu >> 16)) + accy, 0.f);
    if (out_f32) {
        *(float2*)(out_f32 + (size_t)wid * DD + lane * 2) = make_float2(ox, oy);
    }
    if (out_bf16) {
        ushort2 o; o.x = f2bf(ox); o.y = f2bf(oy);
        *(ushort2*)(out_bf16 + (size_t)wid * DD + lane * 2) = o;
    }
}

// ---------------------------------------------------------------------------
// Graph segment sum: gf[n2g[n]] += nf[n] (n2g sorted).
// ---------------------------------------------------------------------------
__global__ __launch_bounds__(256) void graph_sum(
    const float* __restrict__ nf,
    const int* __restrict__ n2g,
    float* __restrict__ gf,
    int N)
{
    int t = blockIdx.x * 256 + threadIdx.x;
    int chunk = t >> 5;
    int lane = t & 31;
    int n0 = chunk * 16;
    if (n0 >= N) return;
    int nend = n0 + 16; if (nend > N) nend = N;

    float4 acc = make_float4(0.f, 0.f, 0.f, 0.f);
    int curg = n2g[n0];
    for (int n = n0; n < nend; ++n) {
        int g = n2g[n];
        if (g != curg) {
            float* dst = gf + (size_t)curg * DD + lane * 4;
            atomicAdd(dst + 0, acc.x); atomicAdd(dst + 1, acc.y);
            atomicAdd(dst + 2, acc.z); atomicAdd(dst + 3, acc.w);
            acc = make_float4(0.f, 0.f, 0.f, 0.f);
            curg = g;
        }
        float4 v = *(const float4*)(nf + (size_t)n * DD + lane * 4);
        acc.x += v.x; acc.y += v.y; acc.z += v.z; acc.w += v.w;
    }
    float* dst = gf + (size_t)curg * DD + lane * 4;
    atomicAdd(dst + 0, acc.x); atomicAdd(dst + 1, acc.y);
    atomicAdd(dst + 2, acc.z); atomicAdd(dst + 3, acc.w);
}

// ---------------------------------------------------------------------------
extern "C" void kernel_launch(void* const* d_in, const int* in_sizes, int n_in,
                              void* d_out, int out_size, void* d_ws, size_t ws_size,
                              hipStream_t stream)
{
    const float* x        = (const float*)d_in[0];
    const int*   node_in  = (const int*)d_in[1];
    const int*   node_out = (const int*)d_in[2];
    const int*   relation = (const int*)d_in[3];
    const float* ew       = (const float*)d_in[4];
    const int*   n2g      = (const int*)d_in[5];
    const float* Wr       = (const float*)d_in[6];
    const float* br       = (const float*)d_in[7];
    const float* Wl       = (const float*)d_in[8];
    const float* bl       = (const float*)d_in[9];

    float* out = (float*)d_out;
    float* gf = out;                 // 16 x 128
    float* nf = out + GG * DD;       // 30000 x 128

    // Workspace layout (~85 MB)
    char* w = (char*)d_ws;
    unsigned short* Zb   = (unsigned short*)w; w += (size_t)NN * RR * DD * 2;   // 53.76 MB
    unsigned short* haccb= (unsigned short*)w; w += (size_t)NN * DD * 2;        // 7.68 MB
    unsigned short* hbA  = (unsigned short*)w; w += (size_t)NN * DD * 2;        // 7.68 MB
    unsigned short* hbB  = (unsigned short*)w; w += (size_t)NN * DD * 2;        // 7.68 MB
    unsigned short* Bw   = (unsigned short*)w; w += (size_t)LL * 1024 * DD * 2; // 0.79 MB
    int2*  meta   = (int2*)w;                  w += (size_t)NE * 8;             // 4.8 MB
    int*   start  = (int*)w;                   w += (size_t)(NN + 1) * 4 + 60;
    int*   cursor = (int*)w;                   w += (size_t)NN * 4 + 64;
    int*   cnt    = (int*)w;                   w += (size_t)NN * 4 + 64;
    int*   lscan  = (int*)w;                   w += (size_t)NN * 4 + 64;
    int*   bsum   = (int*)w;                   w += 256 * 4;
    int*   boff   = (int*)w;                   w += 256 * 4;

    const int N = NN, E = NE;
    const int NB = (N + 255) / 256;            // 118

    // ---- once per call: weight pack, x->bf16, edge sort --------------------
    pack_weights<<<(LL * 1024 * DD + 255) / 256, 256, 0, stream>>>(Wl, Wr, Bw);
    convert_bf16<<<(N * DD / 4 + 255) / 256, 256, 0, stream>>>(x, hbA, N * DD / 4);

    hipMemsetAsync(cnt, 0, (size_t)N * sizeof(int), stream);
    edge_hist<<<(E + 255) / 256, 256, 0, stream>>>(node_out, cnt, E);
    scan_blk<<<NB, 256, 0, stream>>>(cnt, lscan, bsum, N);
    scan_bsum<<<1, 128, 0, stream>>>(bsum, boff, NB);
    scan_add<<<(N + 256) / 256, 256, 0, stream>>>(lscan, boff, start, cursor, N);
    edge_scatter_sort<<<(E + 255) / 256, 256, 0, stream>>>(
        node_in, node_out, relation, ew, cursor, meta, E);

    // ---- layers ----
    dim3 ggrid((N + 63) / 64, 8);
    unsigned short* hin = hbA;
    unsigned short* hnext = hbB;
    for (int l = 0; l < LL; ++l) {
        const float* br_l = br + (size_t)l * DD;
        const float* bl_l = bl + (size_t)l * DD;
        const unsigned short* Bw_l = Bw + (size_t)l * 1024 * DD;

        gemm_mfma<<<ggrid, 256, 0, stream>>>(hin, Bw_l, br_l, bl_l, haccb, Zb, N);

        bool last = (l == LL - 1);
        aggregate<<<(N * 64 + 255) / 256, 256, 0, stream>>>(
            Zb, start, meta, haccb,
            last ? nf : (float*)nullptr,
            last ? (unsigned short*)nullptr : hnext, N);

        unsigned short* t = hin; hin = hnext; hnext = t;
    }

    // ---- graph_feature ----
    hipMemsetAsync(gf, 0, (size_t)GG * DD * sizeof(float), stream);
    int chunks = (N + 15) / 16;
    graph_sum<<<(chunks * 32 + 255) / 256, 256, 0, stream>>>(nf, n2g, gf, N);
}

// Round 6
// 344.441 us; speedup vs baseline: 10.2387x; 1.0054x over previous
//
#include <hip/hip_runtime.h>
#include <hip/hip_bf16.h>

// Problem constants (match reference setup_inputs)
#define NN 30000      // nodes
#define NE 600000     // edges
#define DD 128        // feature dim
#define RR 7          // relations
#define GG 16         // graphs
#define LL 3          // layers

#define NB64 ((NN + 63) / 64)   // 469 buckets of 64 nodes

typedef short bf16x8 __attribute__((ext_vector_type(8)));  // 8 bf16 = 4 VGPRs
typedef float f32x4  __attribute__((ext_vector_type(4)));

// ---- bf16 helpers ----------------------------------------------------------
__device__ __forceinline__ unsigned short f2bf(float f) {
    unsigned u = __float_as_uint(f);
    unsigned r = (u + 0x7fffu + ((u >> 16) & 1u)) >> 16;   // round-nearest-even
    return (unsigned short)r;
}
__device__ __forceinline__ float bf2f(unsigned short b) {
    return __uint_as_float(((unsigned)b) << 16);
}
// packed f32x2 -> bf16x2 (v_cvt_pk_bf16_f32 on gfx950)
__device__ __forceinline__ ushort2 pk2bf(float a, float b) {
    __hip_bfloat162 t = __float22bfloat162_rn(make_float2(a, b));
    return *(ushort2*)&t;
}

// async global->LDS, 16B per lane; LDS dest = wave-uniform base + lane*16
__device__ __forceinline__ void gl_lds16(const void* g, void* l) {
    __builtin_amdgcn_global_load_lds(
        (const __attribute__((address_space(1))) void*)g,
        (__attribute__((address_space(3))) void*)l, 16, 0, 0);
}

// ---------------------------------------------------------------------------
// Weight pack: Bw[l][n][k] (bf16, n-major) from fp32 Wl (k-major 128x128) and
// Wr (896x128; block r rows, B[k][c] -> n=128+r*128+c)
// ---------------------------------------------------------------------------
__global__ __launch_bounds__(256) void pack_weights(
    const float* __restrict__ Wl,   // L x 128 x 128
    const float* __restrict__ Wr,   // L x 896 x 128
    unsigned short* __restrict__ Bw)// L x 1024 x 128
{
    int t = blockIdx.x * 256 + threadIdx.x;
    if (t >= LL * 1024 * DD) return;
    int l = t >> 17;
    int rem = t & 131071;
    int n = rem >> 7;
    int k = rem & 127;
    float v;
    if (n < DD) {
        v = Wl[(size_t)l * DD * DD + k * DD + n];
    } else {
        int q = n - DD;
        v = Wr[(size_t)l * RR * DD * DD + (size_t)((q >> 7) * DD + k) * DD + (q & 127)];
    }
    Bw[(size_t)l * 1024 * DD + n * DD + k] = f2bf(v);
}

// x (fp32) -> bf16
__global__ __launch_bounds__(256) void convert_bf16(
    const float* __restrict__ in, unsigned short* __restrict__ out, int n4)
{
    int i = blockIdx.x * 256 + threadIdx.x;
    if (i >= n4) return;
    float4 v = ((const float4*)in)[i];
    ushort2 lo = pk2bf(v.x, v.y);
    ushort2 hi = pk2bf(v.z, v.w);
    ((ushort4*)out)[i] = make_ushort4(lo.x, lo.y, hi.x, hi.y);
}

// ---------------------------------------------------------------------------
// MFMA GEMM: out (N x 1024) = hb (N x 128, bf16) @ B (128 x 1024, bf16)
//   blockIdx.y == 0  -> cols 0..127  -> haccb (bf16, + br + bl)
//   blockIdx.y >= 1  -> cols 128+    -> Zb (bf16)
// Block: 64 rows x 128 cols, 256 threads = 4 waves. Full K=128 in LDS via
// global_load_lds width=16. ASTR=128 (no pad) per gl_lds lane ordering.
// ---------------------------------------------------------------------------
#define ASTR 128
__global__ __launch_bounds__(256) void gemm_mfma(
    const unsigned short* __restrict__ hb,   // N x 128 bf16
    const unsigned short* __restrict__ Bw,   // 1024 x 128 bf16 (n-major)
    const float* __restrict__ br,            // 128
    const float* __restrict__ bl,            // 128
    unsigned short* __restrict__ haccb,      // N x 128 bf16
    unsigned short* __restrict__ Zb,         // N x 896 bf16
    int N)
{
    __shared__ unsigned short As[64 * ASTR];   // 16 KB
    __shared__ unsigned short Bs[128 * ASTR];  // 32 KB

    const int tid  = threadIdx.x;
    const int wave = tid >> 6;
    const int lane = tid & 63;
    const int quad = lane >> 4;
    const int l16  = lane & 15;
    const int row0 = blockIdx.x * 64;
    const int col0 = blockIdx.y * 128;       // 0 or 128..896

    // A: 16 wave-issues of 1 KB (4 rows each). Overrun past N lands in the
    // adjacent workspace buffer (safe; outputs masked).
#pragma unroll
    for (int i = 0; i < 4; ++i) {
        int g = i * 4 + wave;                // 0..15
        gl_lds16(hb + (size_t)(row0 + g * 4) * DD + lane * 8,
                 As + g * 512);
    }
    // B: 128x128 tile contiguous 32 KB in Bw -> 32 wave-issues.
#pragma unroll
    for (int i = 0; i < 8; ++i) {
        int g = i * 4 + wave;                // 0..31
        gl_lds16(Bw + (size_t)col0 * DD + (size_t)g * 512 + lane * 8,
                 Bs + g * 512);
    }
    __syncthreads();

    f32x4 acc[4][2];
#pragma unroll
    for (int mt = 0; mt < 4; ++mt)
#pragma unroll
        for (int nt = 0; nt < 2; ++nt)
            acc[mt][nt] = (f32x4){0.f, 0.f, 0.f, 0.f};

    const unsigned short* As_l = As + l16 * ASTR;
    const unsigned short* Bs_l = Bs + (wave * 32 + l16) * ASTR;

#pragma unroll
    for (int kc = 0; kc < 4; ++kc) {
        int ko = kc * 32 + quad * 8;
        bf16x8 a0 = *(const bf16x8*)(As_l + 0 * 16 * ASTR + ko);
        bf16x8 a1 = *(const bf16x8*)(As_l + 1 * 16 * ASTR + ko);
        bf16x8 a2 = *(const bf16x8*)(As_l + 2 * 16 * ASTR + ko);
        bf16x8 a3 = *(const bf16x8*)(As_l + 3 * 16 * ASTR + ko);
        bf16x8 b0 = *(const bf16x8*)(Bs_l + 0 * 16 * ASTR + ko);
        bf16x8 b1 = *(const bf16x8*)(Bs_l + 1 * 16 * ASTR + ko);
        acc[0][0] = __builtin_amdgcn_mfma_f32_16x16x32_bf16(a0, b0, acc[0][0], 0, 0, 0);
        acc[1][0] = __builtin_amdgcn_mfma_f32_16x16x32_bf16(a1, b0, acc[1][0], 0, 0, 0);
        acc[2][0] = __builtin_amdgcn_mfma_f32_16x16x32_bf16(a2, b0, acc[2][0], 0, 0, 0);
        acc[3][0] = __builtin_amdgcn_mfma_f32_16x16x32_bf16(a3, b0, acc[3][0], 0, 0, 0);
        acc[0][1] = __builtin_amdgcn_mfma_f32_16x16x32_bf16(a0, b1, acc[0][1], 0, 0, 0);
        acc[1][1] = __builtin_amdgcn_mfma_f32_16x16x32_bf16(a1, b1, acc[1][1], 0, 0, 0);
        acc[2][1] = __builtin_amdgcn_mfma_f32_16x16x32_bf16(a2, b1, acc[2][1], 0, 0, 0);
        acc[3][1] = __builtin_amdgcn_mfma_f32_16x16x32_bf16(a3, b1, acc[3][1], 0, 0, 0);
    }

    const int ncol = wave * 32 + l16;
    if (col0 == 0) {
        float bias0 = br[ncol] + bl[ncol];
        float bias1 = br[ncol + 16] + bl[ncol + 16];
#pragma unroll
        for (int mt = 0; mt < 4; ++mt) {
#pragma unroll
            for (int reg = 0; reg < 4; ++reg) {
                int row = row0 + mt * 16 + quad * 4 + reg;
                if (row < N) {
                    ushort2 p = pk2bf(acc[mt][0][reg] + bias0,
                                      acc[mt][1][reg] + bias1);
                    haccb[(size_t)row * DD + ncol]      = p.x;
                    haccb[(size_t)row * DD + ncol + 16] = p.y;
                }
            }
        }
    } else {
        const int zc = col0 - DD + ncol;
#pragma unroll
        for (int mt = 0; mt < 4; ++mt) {
#pragma unroll
            for (int reg = 0; reg < 4; ++reg) {
                int row = row0 + mt * 16 + quad * 4 + reg;
                if (row < N) {
                    ushort2 p = pk2bf(acc[mt][0][reg], acc[mt][1][reg]);
                    Zb[(size_t)row * (RR * DD) + zc]      = p.x;
                    Zb[(size_t)row * (RR * DD) + zc + 16] = p.y;
                }
            }
        }
    }
}

// ---------------------------------------------------------------------------
// Bucketed edge sort (2 passes). Buckets of 64 consecutive out-nodes.
// Counters padded to 64 B to avoid same-line atomic serialization.
// ---------------------------------------------------------------------------
__global__ __launch_bounds__(256) void bucket_hist(
    const int* __restrict__ node_out, int* __restrict__ bcnt, int E)
{
    int e = blockIdx.x * 256 + threadIdx.x;
    if (e < E) atomicAdd(&bcnt[(node_out[e] >> 6) * 16], 1);
}

// Exclusive scan of 469 bucket counts (single block, 512 threads).
__global__ __launch_bounds__(512) void bucket_scan(
    const int* __restrict__ bcnt, int* __restrict__ bstart,
    int* __restrict__ bcur, int nb)
{
    __shared__ int s[512];
    int t = threadIdx.x;
    int v = (t < nb) ? bcnt[t * 16] : 0;
    s[t] = v;
    __syncthreads();
#pragma unroll
    for (int off = 1; off < 512; off <<= 1) {
        int u = (t >= off) ? s[t - off] : 0;
        __syncthreads();
        s[t] += u;
        __syncthreads();
    }
    if (t <= nb) {
        int excl = s[t] - v;                 // for t==nb: v==0 -> total
        bstart[t] = excl;
        if (t < nb) bcur[t * 16] = excl;
    }
}

// Pass A: append edges to their bucket (packed payload).
// pack.x = (out&63)<<18 | in<<3 | rel   (in<30000 -> in*8+rel < 2^18)
__global__ __launch_bounds__(256) void bucket_scatter(
    const int* __restrict__ node_in,
    const int* __restrict__ node_out,
    const int* __restrict__ relation,
    const float* __restrict__ ew,
    int* __restrict__ bcur,
    int2* __restrict__ tmp,
    int E)
{
    int e = blockIdx.x * 256 + threadIdx.x;
    if (e >= E) return;
    int o = node_out[e];
    int pos = atomicAdd(&bcur[(o >> 6) * 16], 1);
    tmp[pos] = make_int2(((o & 63) << 18) | (node_in[e] << 3) | relation[e],
                         __float_as_int(ew[e]));
}

// Pass B: one block per bucket. LDS counting sort over the 64 local nodes;
// emits meta (zoff, w) in node order AND the global start[] array.
__global__ __launch_bounds__(256) void bucket_sort(
    const int2* __restrict__ tmp,
    const int* __restrict__ bstart,
    int2* __restrict__ meta,
    int* __restrict__ start,
    int N)
{
    __shared__ int hist[64];
    __shared__ int scan[64];
    __shared__ int cur[64];
    const int b = blockIdx.x;
    const int t = threadIdx.x;
    const int s0 = bstart[b];
    const int s1 = bstart[b + 1];

    if (t < 64) hist[t] = 0;
    __syncthreads();
    for (int i = s0 + t; i < s1; i += 256)
        atomicAdd(&hist[((unsigned)tmp[i].x) >> 18], 1);
    __syncthreads();

    int v = (t < 64) ? hist[t] : 0;
    if (t < 64) scan[t] = v;
    __syncthreads();
#pragma unroll
    for (int off = 1; off < 64; off <<= 1) {
        int u = (t < 64 && t >= off) ? scan[t - off] : 0;
        __syncthreads();
        if (t < 64) scan[t] += u;
        __syncthreads();
    }
    if (t < 64) {
        int excl = scan[t] - v;
        cur[t] = s0 + excl;
        int node = b * 64 + t;
        if (node <= N) start[node] = s0 + excl;   // node==N -> start[N]=E
    }
    __syncthreads();

    for (int i = s0 + t; i < s1; i += 256) {
        int2 m = tmp[i];
        int j = ((unsigned)m.x) >> 18;
        int pos = atomicAdd(&cur[j], 1);
        int key = m.x & 0x3ffff;
        int in = key >> 3, rel = key & 7;
        meta[pos] = make_int2((in * RR + rel) << 7, m.y);
    }
}

// ---------------------------------------------------------------------------
// Aggregate: o[n] = relu(haccb[n] + sum_{e in edges(n)} w_e * Zb[zoff_e][:])
// One 64-lane wave per node, lane owns 2 columns. Edge loop unrolled x8.
// ---------------------------------------------------------------------------
__global__ __launch_bounds__(256) void aggregate(
    const unsigned short* __restrict__ Zb,  // N x 896 bf16
    const int* __restrict__ start,          // N+1
    const int2* __restrict__ meta,          // E
    const unsigned short* __restrict__ haccb, // N x 128 bf16
    float* __restrict__ out_f32,            // N x 128 or null
    unsigned short* __restrict__ out_bf16,  // N x 128 or null
    int N)
{
    int wid = (blockIdx.x * 256 + threadIdx.x) >> 6;
    int lane = threadIdx.x & 63;
    if (wid >= N) return;

    int e0 = start[wid];
    int e1 = start[wid + 1];

    float accx = 0.f, accy = 0.f;
    int e = e0;
    for (; e + 8 <= e1; e += 8) {
        unsigned u[8]; float wt[8];
#pragma unroll
        for (int j = 0; j < 8; ++j) {
            int2 m = meta[e + j];
            u[j] = *(const unsigned*)(Zb + m.x + lane * 2);
            wt[j] = __int_as_float(m.y);
        }
#pragma unroll
        for (int j = 0; j < 8; ++j) {
            accx = fmaf(wt[j], __uint_as_float(u[j] << 16), accx);
            accy = fmaf(wt[j], __uint_as_float(u[j] & 0xffff0000u), accy);
        }
    }
    for (; e + 2 <= e1; e += 2) {
        int2 m0 = meta[e];
        int2 m1 = meta[e + 1];
        unsigned u0 = *(const unsigned*)(Zb + m0.x + lane * 2);
        unsigned u1 = *(const unsigned*)(Zb + m1.x + lane * 2);
        float w0 = __int_as_float(m0.y), w1 = __int_as_float(m1.y);
        accx = fmaf(w0, __uint_as_float(u0 << 16), accx);
        accy = fmaf(w0, __uint_as_float(u0 & 0xffff0000u), accy);
        accx = fmaf(w1, __uint_as_float(u1 << 16), accx);
        accy = fmaf(w1, __uint_as_float(u1 & 0xffff0000u), accy);
    }
    if (e < e1) {
        int2 m = meta[e];
        unsigned u = *(const unsigned*)(Zb + m.x + lane * 2);
        float wt = __int_as_float(m.y);
        accx = fmaf(wt, __uint_as_float(u << 16), accx);
        accy = fmaf(wt, __uint_as_float(u & 0xffff0000u), accy);
    }

    unsigned bu = *(const unsigned*)(haccb + (size_t)wid * DD + lane * 2);
    float ox = fmaxf(bf2f((unsigned short)(bu & 0xffffu)) + accx, 0.f);
    float oy = fmaxf(bf2f((unsigned short)(bu >> 16)) + accy, 0.f);
    if (out_f32) {
        *(float2*)(out_f32 + (size_t)wid * DD + lane * 2) = make_float2(ox, oy);
    }
    if (out_bf16) {
        ushort2 o = pk2bf(ox, oy);
        *(ushort2*)(out_bf16 + (size_t)wid * DD + lane * 2) = o;
    }
}

// ---------------------------------------------------------------------------
// Graph segment sum: gf[n2g[n]] += nf[n] (n2g sorted).
// ---------------------------------------------------------------------------
__global__ __launch_bounds__(256) void graph_sum(
    const float* __restrict__ nf,
    const int* __restrict__ n2g,
    float* __restrict__ gf,
    int N)
{
    int t = blockIdx.x * 256 + threadIdx.x;
    int chunk = t >> 5;
    int lane = t & 31;
    int n0 = chunk * 16;
    if (n0 >= N) return;
    int nend = n0 + 16; if (nend > N) nend = N;

    float4 acc = make_float4(0.f, 0.f, 0.f, 0.f);
    int curg = n2g[n0];
    for (int n = n0; n < nend; ++n) {
        int g = n2g[n];
        if (g != curg) {
            float* dst = gf + (size_t)curg * DD + lane * 4;
            atomicAdd(dst + 0, acc.x); atomicAdd(dst + 1, acc.y);
            atomicAdd(dst + 2, acc.z); atomicAdd(dst + 3, acc.w);
            acc = make_float4(0.f, 0.f, 0.f, 0.f);
            curg = g;
        }
        float4 v = *(const float4*)(nf + (size_t)n * DD + lane * 4);
        acc.x += v.x; acc.y += v.y; acc.z += v.z; acc.w += v.w;
    }
    float* dst = gf + (size_t)curg * DD + lane * 4;
    atomicAdd(dst + 0, acc.x); atomicAdd(dst + 1, acc.y);
    atomicAdd(dst + 2, acc.z); atomicAdd(dst + 3, acc.w);
}

// ---------------------------------------------------------------------------
extern "C" void kernel_launch(void* const* d_in, const int* in_sizes, int n_in,
                              void* d_out, int out_size, void* d_ws, size_t ws_size,
                              hipStream_t stream)
{
    const float* x        = (const float*)d_in[0];
    const int*   node_in  = (const int*)d_in[1];
    const int*   node_out = (const int*)d_in[2];
    const int*   relation = (const int*)d_in[3];
    const float* ew       = (const float*)d_in[4];
    const int*   n2g      = (const int*)d_in[5];
    const float* Wr       = (const float*)d_in[6];
    const float* br       = (const float*)d_in[7];
    const float* Wl       = (const float*)d_in[8];
    const float* bl       = (const float*)d_in[9];

    float* out = (float*)d_out;
    float* gf = out;                 // 16 x 128
    float* nf = out + GG * DD;       // 30000 x 128

    // Workspace layout (~88 MB)
    char* w = (char*)d_ws;
    unsigned short* Zb   = (unsigned short*)w; w += (size_t)NN * RR * DD * 2;   // 53.76 MB
    unsigned short* haccb= (unsigned short*)w; w += (size_t)NN * DD * 2;        // 7.68 MB
    unsigned short* hbA  = (unsigned short*)w; w += (size_t)NN * DD * 2;        // 7.68 MB
    unsigned short* hbB  = (unsigned short*)w; w += (size_t)NN * DD * 2;        // 7.68 MB
    unsigned short* Bw   = (unsigned short*)w; w += (size_t)LL * 1024 * DD * 2; // 0.79 MB
    int2*  meta   = (int2*)w;                  w += (size_t)NE * 8;             // 4.8 MB
    int2*  tmp    = (int2*)w;                  w += (size_t)NE * 8;             // 4.8 MB
    int*   start  = (int*)w;                   w += (size_t)(NN + 1) * 4 + 60;
    int*   bcnt   = (int*)w;                   w += (size_t)NB64 * 16 * 4 + 64;
    int*   bcur   = (int*)w;                   w += (size_t)NB64 * 16 * 4 + 64;
    int*   bstart = (int*)w;                   w += (size_t)(NB64 + 1) * 4 + 60;

    const int N = NN, E = NE;

    // ---- once per call: weight pack, x->bf16, bucketed edge sort -----------
    pack_weights<<<(LL * 1024 * DD + 255) / 256, 256, 0, stream>>>(Wl, Wr, Bw);
    convert_bf16<<<(N * DD / 4 + 255) / 256, 256, 0, stream>>>(x, hbA, N * DD / 4);

    hipMemsetAsync(bcnt, 0, (size_t)NB64 * 16 * sizeof(int), stream);
    bucket_hist<<<(E + 255) / 256, 256, 0, stream>>>(node_out, bcnt, E);
    bucket_scan<<<1, 512, 0, stream>>>(bcnt, bstart, bcur, NB64);
    bucket_scatter<<<(E + 255) / 256, 256, 0, stream>>>(
        node_in, node_out, relation, ew, bcur, tmp, E);
    bucket_sort<<<NB64, 256, 0, stream>>>(tmp, bstart, meta, start, N);

    // ---- layers ----
    dim3 ggrid((N + 63) / 64, 8);
    unsigned short* hin = hbA;
    unsigned short* hnext = hbB;
    for (int l = 0; l < LL; ++l) {
        const float* br_l = br + (size_t)l * DD;
        const float* bl_l = bl + (size_t)l * DD;
        const unsigned short* Bw_l = Bw + (size_t)l * 1024 * DD;

        gemm_mfma<<<ggrid, 256, 0, stream>>>(hin, Bw_l, br_l, bl_l, haccb, Zb, N);

        bool last = (l == LL - 1);
        aggregate<<<(N * 64 + 255) / 256, 256, 0, stream>>>(
            Zb, start, meta, haccb,
            last ? nf : (float*)nullptr,
            last ? (unsigned short*)nullptr : hnext, N);

        unsigned short* t = hin; hin = hnext; hnext = t;
    }

    // ---- graph_feature ----
    hipMemsetAsync(gf, 0, (size_t)GG * DD * sizeof(float), stream);
    int chunks = (N + 15) / 16;
    graph_sum<<<(chunks * 32 + 255) / 256, 256, 0, stream>>>(nf, n2g, gf, N);
}